// Round 4
// baseline (1724.889 us; speedup 1.0000x reference)
//
#include <hip/hip_runtime.h>
#include <hip/hip_bf16.h>
#include <math.h>

typedef __hip_bfloat16 bf16;
typedef __attribute__((ext_vector_type(8))) short short8;
typedef __attribute__((ext_vector_type(4))) short short4v;
typedef __attribute__((ext_vector_type(4))) float floatx4;
typedef __attribute__((ext_vector_type(2))) unsigned int uint2v;

#define DEV static __device__ __forceinline__

DEV float bf2f(unsigned short u) {
  union { unsigned int i; float f; } x;
  x.i = ((unsigned int)u) << 16;
  return x.f;
}
DEV unsigned short f2bf_bits(float f) {
  union { bf16 h; unsigned short u; } x;
  x.h = __float2bfloat16(f);
  return x.u;
}
DEV short8 cvt8(float4 a, float4 b) {
  short8 r;
  r[0] = (short)f2bf_bits(a.x); r[1] = (short)f2bf_bits(a.y);
  r[2] = (short)f2bf_bits(a.z); r[3] = (short)f2bf_bits(a.w);
  r[4] = (short)f2bf_bits(b.x); r[5] = (short)f2bf_bits(b.y);
  r[6] = (short)f2bf_bits(b.z); r[7] = (short)f2bf_bits(b.w);
  return r;
}

// tanh-form GELU: v * sigmoid(1.5957691*v + 0.0713548*v^3). |err| vs exact ~1e-3.
DEV float gelu_fast(float v) {
  float y = v * (1.5957691216f + 0.0713548163f * v * v);
  return __fdividef(v, 1.f + __expf(-y));
}

// async global->LDS, 16B per lane. LDS dest must be wave-uniform base + lane*16.
DEV void gload_lds16(const unsigned short* g, unsigned short* l) {
  __builtin_amdgcn_global_load_lds((const __attribute__((address_space(1))) void*)g,
                                   (__attribute__((address_space(3))) void*)l,
                                   16, 0, 0);
}

// window-gather (chunk-local): window-row -> source row (fuses roll(-4,-4)+partition)
DEV int gather_win_row(int wr) {
  int bw = wr >> 6, n = wr & 63;
  int bt = bw >> 2, w2 = bw & 3;
  int wi = w2 >> 1, wj = w2 & 1;
  int r = n >> 3, c = n & 7;
  int sr = (wi * 8 + r + 4) & 15;
  int sc = (wj * 8 + c + 4) & 15;
  return bt * 256 + sr * 16 + sc;
}

enum { BIAS_SIMPLE = 0, BIAS_QKV = 1 };
enum { ACT_NONE = 0, ACT_GELU = 1 };

// f32 -> bf16 bulk convert, 8 elems/thread.
__global__ __launch_bounds__(256) void cvt_bf16(const float* __restrict__ in,
                                                bf16* __restrict__ out, int n) {
  int i = (blockIdx.x * 256 + threadIdx.x) * 8;
  if (i >= n) return;
  float4 a = *reinterpret_cast<const float4*>(in + i);
  float4 b = *reinterpret_cast<const float4*>(in + i + 4);
  *reinterpret_cast<short8*>((unsigned short*)out + i) = cvt8(a, b);
}

// ====================== 256x256 8-phase GEMM (T2-layout + T3 + T4 + T5) =====
// C[M,N] = act(A[M,K] @ B[N,K]^T + bias). BM=BN=256, BK=64, 512 thr = 8 waves
// (2M x 4N), per-wave 128x64 output. LDS 128KB dynamic: 2 buffers x
// {A,B} x {ks0,ks1} chunks of [256 rows][32 cols] bf16 (16KB each).
// Chunked [256][32] layout (64B rows) makes the frag ds_read_b128 bank-uniform
// (no swizzle needed on either side). Per K-tile: 4 phases, each = issue 1
// chunk of tile t+1 (2 gload_lds) -> vmcnt(6) -> s_barrier -> ds_read ->
// setprio(1) 16 MFMA setprio(0). Stage order A_k0,B_k0,A_k1,B_k1; consume
// p1:(ks0,ih0)+B0, p2:(ks0,ih1), p3:(ks1,ih0)+B1, p4:(ks1,ih1) -> every chunk
// published >=3 phases before first read (vmcnt(6) = 3 chunks in flight).
#define VMCNT(N_) asm volatile("s_waitcnt vmcnt(" #N_ ")" ::: "memory")
#define BARRIER() do { __builtin_amdgcn_s_barrier(); asm volatile("" ::: "memory"); } while (0)

#define STG(BUF, ISB, KS, KT) do { \
    char* dst_ = smem + (BUF) * 65536 + (ISB) * 32768 + (KS) * 16384; \
    gload_lds16(((ISB) ? bgp[0] : agp[0]) + (KT) * 64 + (KS) * 32, \
                (unsigned short*)(dst_ + soff0)); \
    gload_lds16(((ISB) ? bgp[1] : agp[1]) + (KT) * 64 + (KS) * 32, \
                (unsigned short*)(dst_ + soff1)); \
  } while (0)

#define CONSUME(KS, IH, DO_B) do { \
    const char* ac_ = smem + bsel * 65536 + (KS) * 16384; \
    if (DO_B) { \
      const char* bc_ = ac_ + 32768; \
      _Pragma("unroll") \
      for (int j_ = 0; j_ < 4; ++j_) \
        bfr[j_] = *reinterpret_cast<const short8*>(bc_ + bBase + j_ * 1024); \
    } \
    _Pragma("unroll") \
    for (int i_ = 0; i_ < 4; ++i_) \
      af[i_] = *reinterpret_cast<const short8*>(ac_ + aBase + ((IH) * 4 + i_) * 1024); \
    __builtin_amdgcn_s_setprio(1); \
    _Pragma("unroll") \
    for (int i_ = 0; i_ < 4; ++i_) \
      _Pragma("unroll") \
      for (int j_ = 0; j_ < 4; ++j_) \
        acc[(IH) * 4 + i_][j_] = __builtin_amdgcn_mfma_f32_16x16x32_bf16( \
            af[i_], bfr[j_], acc[(IH) * 4 + i_][j_], 0, 0, 0); \
    __builtin_amdgcn_s_setprio(0); \
  } while (0)

template <int GATHER, int BIASMODE, int ACT>
__global__ __launch_bounds__(512, 2) void gemm8p(
    const unsigned short* __restrict__ A, const unsigned short* __restrict__ B,
    const float* __restrict__ bias0, const float* __restrict__ bias1,
    bf16* __restrict__ C, int M, int N, int K)
{
  extern __shared__ __align__(16) char smem[];
  const int tid = threadIdx.x;
  const int lane = tid & 63;
  const int wave = tid >> 6;
  const int wm = wave >> 2, wn = wave & 3;

  // XCD-contiguous bijective block swizzle (grids here have nwg % 8 == 0)
  const int gx = gridDim.x;
  const int nwg = gx * gridDim.y;
  int lin = blockIdx.y * gx + blockIdx.x;
  if ((nwg & 7) == 0) lin = (lin & 7) * (nwg >> 3) + (lin >> 3);
  const int tileM = (lin % gx) * 256;
  const int tileN = (lin / gx) * 256;

  // staging: slot s = u*512+tid -> row = s>>2, 8-col group = s&3
  const unsigned short* agp[2];
  const unsigned short* bgp[2];
#pragma unroll
  for (int u = 0; u < 2; ++u) {
    int s = u * 512 + tid;
    int row = s >> 2, slot = s & 3;
    int gr = tileM + row;
    int sr = GATHER ? gather_win_row(gr) : gr;
    agp[u] = A + (size_t)sr * (size_t)K + slot * 8;
    bgp[u] = B + (size_t)(tileN + row) * (size_t)K + slot * 8;
  }
  const int soff0 = tid * 16;
  const int soff1 = (512 + tid) * 16;

  // frag read bases (chunk rows are 64B)
  const int aBase = (wm * 128 + (lane & 15)) * 64 + (lane >> 4) * 16;
  const int bBase = (wn * 64 + (lane & 15)) * 64 + (lane >> 4) * 16;

  floatx4 acc[8][4];
#pragma unroll
  for (int i = 0; i < 8; ++i)
#pragma unroll
    for (int j = 0; j < 4; ++j) acc[i][j] = (floatx4){0.f, 0.f, 0.f, 0.f};

  short8 af[4], bfr[4];
  const int NT = K >> 6;
  int bsel = 0;

  // prologue: stage tile 0 fully
  STG(0, 0, 0, 0); STG(0, 1, 0, 0); STG(0, 0, 1, 0); STG(0, 1, 1, 0);
  VMCNT(0);
  BARRIER();

  for (int t = 0; t < NT - 1; ++t) {
    const int nb = bsel ^ 1;
    const int kt1 = t + 1;
    STG(nb, 0, 0, kt1); VMCNT(6); BARRIER(); CONSUME(0, 0, 1);
    STG(nb, 1, 0, kt1); VMCNT(6); BARRIER(); CONSUME(0, 1, 0);
    STG(nb, 0, 1, kt1); VMCNT(6); BARRIER(); CONSUME(1, 0, 1);
    STG(nb, 1, 1, kt1); VMCNT(6); BARRIER(); CONSUME(1, 1, 0);
    bsel = nb;
  }
  // last tile: drain in two counted steps (never over-waits earlier)
  VMCNT(4); BARRIER();
  CONSUME(0, 0, 1);
  CONSUME(0, 1, 0);
  VMCNT(0); BARRIER();
  CONSUME(1, 0, 1);
  CONSUME(1, 1, 0);

  // ---- epilogue: bias+act, two 128-row rounds through LDS, dwordx4 stores ----
  __syncthreads();
  unsigned short* sh16 = (unsigned short*)smem;
  const int g = lane >> 4, q = lane & 15;
  float bv[4];
#pragma unroll
  for (int j = 0; j < 4; ++j) {
    const int colG = tileN + wn * 64 + j * 16 + q;
    if (BIASMODE == BIAS_QKV) {
      bv[j] = (colG < 1024) ? bias0[colG] : (colG < 2048 ? 0.f : bias1[colG - 2048]);
    } else {
      bv[j] = bias0[colG];
    }
  }
#pragma unroll
  for (int h = 0; h < 2; ++h) {
    if (wm == h) {
#pragma unroll
      for (int i = 0; i < 8; ++i)
#pragma unroll
        for (int j = 0; j < 4; ++j)
#pragma unroll
          for (int r = 0; r < 4; ++r) {
            float v = acc[i][j][r] + bv[j];
            if (ACT == ACT_GELU) v = gelu_fast(v);
            sh16[(i * 16 + g * 4 + r) * 264 + wn * 64 + j * 16 + q] = f2bf_bits(v);
          }
    }
    __syncthreads();
#pragma unroll
    for (int pass = 0; pass < 8; ++pass) {
      const int idx = pass * 512 + tid;
      const int row = idx >> 5, c16 = idx & 31;
      uint4 val = *reinterpret_cast<const uint4*>(&sh16[row * 264 + c16 * 8]);
      *reinterpret_cast<uint4*>(
          (unsigned short*)C + (size_t)(tileM + h * 128 + row) * (size_t)N +
          tileN + c16 * 8) = val;
    }
    __syncthreads();
  }
}

// ============== fallback 128x128 GEMM (round-3 verified) ====================
template <int GATHER, int BIASMODE, int ACT>
__global__ __launch_bounds__(256, 2) void gemm_bt(
    const unsigned short* __restrict__ A, const unsigned short* __restrict__ B,
    const float* __restrict__ bias0, const float* __restrict__ bias1,
    bf16* __restrict__ C, int M, int N, int K)
{
  __shared__ __align__(16) unsigned short sh[128 * 136];
  unsigned short* As = sh;
  unsigned short* Bs = sh + 8192;

  const int tid = threadIdx.x;
  const int lane = tid & 63;
  const int wave = tid >> 6;
  const int waveM = wave >> 1, waveN = wave & 1;
  const int tileM = blockIdx.x * 128, tileN = blockIdx.y * 128;

  const int row0 = tid >> 3;
  const int kOff = (tid & 7) * 8;

  const unsigned short* ag[4];
  const unsigned short* bg[4];
  unsigned short* al[4];
  unsigned short* bl[4];
#pragma unroll
  for (int t = 0; t < 4; ++t) {
    int gr = tileM + row0 + 32 * t;
    int sr = GATHER ? gather_win_row(gr) : gr;
    ag[t] = A + (size_t)sr * (size_t)K + (size_t)kOff;
    bg[t] = B + (size_t)(tileN + row0 + 32 * t) * (size_t)K + (size_t)kOff;
    al[t] = &As[(row0 + 32 * t) * 64 + kOff];
    bl[t] = &Bs[(row0 + 32 * t) * 64 + kOff];
  }

  floatx4 acc[4][4];
#pragma unroll
  for (int i = 0; i < 4; ++i)
#pragma unroll
    for (int j = 0; j < 4; ++j) acc[i][j] = (floatx4){0.f, 0.f, 0.f, 0.f};

  for (int k0 = 0; k0 < K; k0 += 64) {
#pragma unroll
    for (int t = 0; t < 4; ++t) {
      gload_lds16(ag[t] + k0, al[t]);
      gload_lds16(bg[t] + k0, bl[t]);
    }
    __syncthreads();
#pragma unroll
    for (int ks = 0; ks < 2; ++ks) {
      const int kk = ks * 32 + (lane >> 4) * 8;
      short8 afv[4], bfv[4];
#pragma unroll
      for (int i = 0; i < 4; ++i)
        afv[i] = *reinterpret_cast<const short8*>(
            &As[(waveM * 64 + i * 16 + (lane & 15)) * 64 + kk]);
#pragma unroll
      for (int j = 0; j < 4; ++j)
        bfv[j] = *reinterpret_cast<const short8*>(
            &Bs[(waveN * 64 + j * 16 + (lane & 15)) * 64 + kk]);
#pragma unroll
      for (int i = 0; i < 4; ++i)
#pragma unroll
        for (int j = 0; j < 4; ++j)
          acc[i][j] = __builtin_amdgcn_mfma_f32_16x16x32_bf16(afv[i], bfv[j], acc[i][j], 0, 0, 0);
    }
    __syncthreads();
  }

#pragma unroll
  for (int j = 0; j < 4; ++j) {
    const int colL = waveN * 64 + j * 16 + (lane & 15);
    const int colG = tileN + colL;
    float bv;
    if (BIASMODE == BIAS_QKV) {
      if (colG < 1024) bv = bias0[colG];
      else if (colG < 2048) bv = 0.f;
      else bv = bias1[colG - 2048];
    } else {
      bv = bias0[colG];
    }
#pragma unroll
    for (int i = 0; i < 4; ++i) {
      const int rL = waveM * 64 + i * 16 + ((lane >> 4) * 4);
#pragma unroll
      for (int r = 0; r < 4; ++r) {
        float v = acc[i][j][r] + bv;
        if (ACT == ACT_GELU) v = gelu_fast(v);
        sh[(rL + r) * 136 + colL] = f2bf_bits(v);
      }
    }
  }
  __syncthreads();
  {
    const int rowR = tid >> 4;
    const int colR = (tid & 15) * 8;
#pragma unroll
    for (int s = 0; s < 8; ++s) {
      const int row = s * 16 + rowR;
      uint4 val = *reinterpret_cast<const uint4*>(&sh[row * 136 + colR]);
      *reinterpret_cast<uint4*>(
          (unsigned short*)C + (size_t)(tileM + row) * (size_t)N + tileN + colR) = val;
    }
  }
}

// CPB MLP: regenerate the static log-spaced coord table and run 2->512->16 MLP.
// TBL layout: [16 heads][225] f32 (head-major for wave-contiguous loads).
__global__ __launch_bounds__(512) void cpb_kernel(
    const float* __restrict__ w1, const float* __restrict__ b1,
    const float* __restrict__ w2, float* __restrict__ TBL)
{
  __shared__ float hid[512];
  const int i = blockIdx.x;   // 0..224
  const int j = threadIdx.x;  // 0..511
  const float d0 = ((float)(i / 15) - 7.f) / 7.f;
  const float d1 = ((float)(i % 15) - 7.f) / 7.f;
  const float t0 = copysignf(log2f(1.f + fabsf(d0)), d0);
  const float t1 = copysignf(log2f(1.f + fabsf(d1)), d1);
  float hv = t0 * w1[j * 2] + t1 * w1[j * 2 + 1] + b1[j];
  hid[j] = fmaxf(hv, 0.f);
  __syncthreads();
  if (j < 16) {
    float s = 0.f;
    for (int jj = 0; jj < 512; ++jj) s += w2[j * 512 + jj] * hid[jj];
    TBL[j * 225 + i] = 16.f / (1.f + expf(-s));
  }
}

// MFMA attention: one wave per (window, head); block = 1 window x 4 heads.
__global__ __launch_bounds__(256) void attn_mfma(
    const bf16* __restrict__ QKV, const float* __restrict__ TBL,
    const float* __restrict__ ls, bf16* __restrict__ ATT)
{
  __shared__ __align__(16) unsigned short Ps[4][64][72];
  __shared__ float tbs[4][226];
  __shared__ int ids[64];

  const int tid = threadIdx.x;
  const int w = tid >> 6;
  const int l = tid & 63;
  const int q = l & 15;
  const int g = l >> 4;
  const int bw = blockIdx.x >> 2;
  const int h = (blockIdx.x & 3) * 4 + w;

  const unsigned short* qkvu = (const unsigned short*)QKV;
  const size_t rbase = (size_t)(bw * 64) * 3072;

  if (tid < 64) {
    const int w2 = bw & 3, wi = w2 >> 1, wj = w2 & 1;
    const int r = tid >> 3, c = tid & 7;
    const int rr = (wi == 0) ? 0 : (r < 4 ? 1 : 2);
    const int rc = (wj == 0) ? 0 : (c < 4 ? 1 : 2);
    ids[tid] = rr * 3 + rc;
  }
#pragma unroll
  for (int i = 0; i < 4; ++i) {
    int idx = i * 64 + l;
    if (idx < 225) tbs[w][idx] = TBL[h * 225 + idx];
  }
  __syncthreads();

  short8 kf[4][2], qf[4][2];
#pragma unroll
  for (int i = 0; i < 4; ++i) {
    const unsigned short* rp = qkvu + rbase + (size_t)(16 * i + q) * 3072 + h * 64 + g * 8;
    qf[i][0] = *reinterpret_cast<const short8*>(rp);
    qf[i][1] = *reinterpret_cast<const short8*>(rp + 32);
    kf[i][0] = *reinterpret_cast<const short8*>(rp + 1024);
    kf[i][1] = *reinterpret_cast<const short8*>(rp + 1024 + 32);
  }

  float rk4[4], rq4[4];
#pragma unroll
  for (int i = 0; i < 4; ++i) {
    float sk = 0.f, sq = 0.f;
#pragma unroll
    for (int ks = 0; ks < 2; ++ks)
#pragma unroll
      for (int e = 0; e < 8; ++e) {
        float kv = bf2f((unsigned short)kf[i][ks][e]);
        float qv = bf2f((unsigned short)qf[i][ks][e]);
        sk += kv * kv; sq += qv * qv;
      }
    sk += __shfl_xor(sk, 16); sk += __shfl_xor(sk, 32);
    sq += __shfl_xor(sq, 16); sq += __shfl_xor(sq, 32);
    rk4[i] = 1.f / fmaxf(sqrtf(sk), 1e-12f);
    rq4[i] = 1.f / fmaxf(sqrtf(sq), 1e-12f);
  }
  const float scl = expf(fminf(ls[h], 4.60517019f));
  float rqs[4];
#pragma unroll
  for (int j = 0; j < 4; ++j) rqs[j] = rq4[j] * scl;

  floatx4 acc[4][4];
#pragma unroll
  for (int i = 0; i < 4; ++i)
#pragma unroll
    for (int j = 0; j < 4; ++j) acc[i][j] = (floatx4){0.f, 0.f, 0.f, 0.f};
#pragma unroll
  for (int ks = 0; ks < 2; ++ks)
#pragma unroll
    for (int i = 0; i < 4; ++i)
#pragma unroll
      for (int j = 0; j < 4; ++j)
        acc[i][j] = __builtin_amdgcn_mfma_f32_16x16x32_bf16(kf[i][ks], qf[j][ks], acc[i][j], 0, 0, 0);

  short8 vf[4][2];
  const unsigned short* vbase = qkvu + rbase + 2048 + h * 64;
#pragma unroll
  for (int jp = 0; jp < 4; ++jp)
#pragma unroll
    for (int ks = 0; ks < 2; ++ks) {
      const int m0 = ks * 32 + g * 8;
      const unsigned short* vp = vbase + 16 * jp + q;
      union { short8 v; unsigned short u[8]; } pk;
#pragma unroll
      for (int e = 0; e < 8; ++e)
        pk.u[e] = vp[(size_t)(m0 + e) * 3072];
      vf[jp][ks] = pk.v;
    }

  int idn[4], rtn[4], ctn[4];
#pragma unroll
  for (int j = 0; j < 4; ++j) {
    const int n = 16 * j + q;
    rtn[j] = n >> 3; ctn[j] = n & 7; idn[j] = ids[n];
  }
#pragma unroll
  for (int i = 0; i < 4; ++i) {
#pragma unroll
    for (int r = 0; r < 4; ++r) {
      const int m = 16 * i + 4 * g + r;
      const float rkm = __shfl(rk4[i], 4 * g + r);
      const int rm = m >> 3, cm = m & 7;
      const int idm = ids[m];
#pragma unroll
      for (int j = 0; j < 4; ++j) {
        float v = acc[i][j][r] * (rkm * rqs[j]) +
                  tbs[w][(rtn[j] - rm + 7) * 15 + (ctn[j] - cm + 7)];
        if (idm != idn[j]) v -= 100.f;
        acc[i][j][r] = v;
      }
    }
  }

  float rs4[4];
#pragma unroll
  for (int j = 0; j < 4; ++j) {
    float mx = acc[0][j][0];
#pragma unroll
    for (int i = 0; i < 4; ++i)
#pragma unroll
      for (int r = 0; r < 4; ++r) mx = fmaxf(mx, acc[i][j][r]);
    mx = fmaxf(mx, __shfl_xor(mx, 16));
    mx = fmaxf(mx, __shfl_xor(mx, 32));
    float sm = 0.f;
#pragma unroll
    for (int i = 0; i < 4; ++i)
#pragma unroll
      for (int r = 0; r < 4; ++r) {
        float e = __expf(acc[i][j][r] - mx);
        acc[i][j][r] = e; sm += e;
      }
    sm += __shfl_xor(sm, 16);
    sm += __shfl_xor(sm, 32);
    rs4[j] = 1.f / sm;
  }

#pragma unroll
  for (int j = 0; j < 4; ++j)
#pragma unroll
    for (int i = 0; i < 4; ++i) {
      uint2v pw;
      pw[0] = (unsigned int)f2bf_bits(acc[i][j][0]) |
              ((unsigned int)f2bf_bits(acc[i][j][1]) << 16);
      pw[1] = (unsigned int)f2bf_bits(acc[i][j][2]) |
              ((unsigned int)f2bf_bits(acc[i][j][3]) << 16);
      *reinterpret_cast<uint2v*>(&Ps[w][16 * j + q][16 * i + 4 * g]) = pw;
    }

  floatx4 o[4][4];
#pragma unroll
  for (int i = 0; i < 4; ++i)
#pragma unroll
    for (int j = 0; j < 4; ++j) o[i][j] = (floatx4){0.f, 0.f, 0.f, 0.f};
#pragma unroll
  for (int ks = 0; ks < 2; ++ks) {
    short8 pa[4];
#pragma unroll
    for (int i2 = 0; i2 < 4; ++i2)
      pa[i2] = *reinterpret_cast<const short8*>(&Ps[w][16 * i2 + q][ks * 32 + g * 8]);
#pragma unroll
    for (int i2 = 0; i2 < 4; ++i2)
#pragma unroll
      for (int j2 = 0; j2 < 4; ++j2)
        o[i2][j2] = __builtin_amdgcn_mfma_f32_16x16x32_bf16(pa[i2], vf[j2][ks], o[i2][j2], 0, 0, 0);
  }

  unsigned short* op = (unsigned short*)ATT + (size_t)(bw * 64) * 1024 + h * 64;
#pragma unroll
  for (int i2 = 0; i2 < 4; ++i2)
#pragma unroll
    for (int r = 0; r < 4; ++r) {
      const float rsn = __shfl(rs4[i2], 4 * g + r);
      const int row = 16 * i2 + 4 * g + r;
#pragma unroll
      for (int j2 = 0; j2 < 4; ++j2)
        op[(size_t)row * 1024 + 16 * j2 + q] = f2bf_bits(o[i2][j2][r] * rsn);
    }
}

// out[tok] = base[tok] + LN(src[maprow(tok)]). One WAVE per token, 4 tokens/block.
template <bool GATHER, bool WB>
__global__ __launch_bounds__(256) void ln_residual(
    const bf16* __restrict__ src, const float* base,
    const float* __restrict__ gw, const float* __restrict__ gb,
    float* out, bf16* __restrict__ out_bf)
{
  const int tok = blockIdx.x * 4 + (threadIdx.x >> 6);
  const int lane = threadIdx.x & 63;
  int srow;
  if (GATHER) {
    const int bt = tok >> 8, rem = tok & 255, i = rem >> 4, j = rem & 15;
    const int p = (i + 12) & 15, qq = (j + 12) & 15;
    srow = (bt * 4 + (p >> 3) * 2 + (qq >> 3)) * 64 + (p & 7) * 8 + (qq & 7);
  } else {
    srow = tok;
  }
  const unsigned short* sp = (const unsigned short*)src + (size_t)srow * 1024 + lane * 16;
  short8 lv0 = *reinterpret_cast<const short8*>(sp);
  short8 lv1 = *reinterpret_cast<const short8*>(sp + 8);
  float v[16];
  float s = 0.f, sq = 0.f;
#pragma unroll
  for (int u = 0; u < 8; ++u) {
    float f = bf2f((unsigned short)lv0[u]); v[u] = f; s += f; sq += f * f;
    float g = bf2f((unsigned short)lv1[u]); v[u + 8] = g; s += g; sq += g * g;
  }
#pragma unroll
  for (int off = 32; off > 0; off >>= 1) { s += __shfl_xor(s, off); sq += __shfl_xor(sq, off); }
  const float mean = s * (1.f / 1024.f);
  const float var = sq * (1.f / 1024.f) - mean * mean;
  const float rstd = rsqrtf(var + 1e-5f);

  const float* bp = base + (size_t)tok * 1024 + lane * 16;
  float* op = out + (size_t)tok * 1024 + lane * 16;
  unsigned short* obp = WB ? ((unsigned short*)out_bf + (size_t)tok * 1024 + lane * 16) : nullptr;
  union { short8 v; unsigned short u[8]; } ob0, ob1;
#pragma unroll
  for (int q4 = 0; q4 < 4; ++q4) {
    float4 b4 = *reinterpret_cast<const float4*>(bp + q4 * 4);
    float bl[4] = {b4.x, b4.y, b4.z, b4.w};
    float4 o4;
    float* ol = (float*)&o4;
#pragma unroll
    for (int u = 0; u < 4; ++u) {
      const int c = lane * 16 + q4 * 4 + u;
      ol[u] = bl[u] + (v[q4 * 4 + u] - mean) * rstd * gw[c] + gb[c];
      if (WB) {
        if (q4 < 2) ob0.u[q4 * 4 + u] = f2bf_bits(ol[u]);
        else ob1.u[(q4 - 2) * 4 + u] = f2bf_bits(ol[u]);
      }
    }
    *reinterpret_cast<float4*>(op + q4 * 4) = o4;
  }
  if (WB) {
    *reinterpret_cast<short8*>(obp) = ob0.v;
    *reinterpret_cast<short8*>(obp + 8) = ob1.v;
  }
}

extern "C" void kernel_launch(void* const* d_in, const int* in_sizes, int n_in,
                              void* d_out, int out_size, void* d_ws, size_t ws_size,
                              hipStream_t stream) {
  (void)in_sizes; (void)n_in; (void)out_size;
  const float* x      = (const float*)d_in[0];
  const float* qkv_w  = (const float*)d_in[1];
  const float* q_bias = (const float*)d_in[2];
  const float* v_bias = (const float*)d_in[3];
  const float* lscale = (const float*)d_in[4];
  const float* cpb_w1 = (const float*)d_in[5];
  const float* cpb_b1 = (const float*)d_in[6];
  const float* cpb_w2 = (const float*)d_in[7];
  const float* proj_w = (const float*)d_in[8];
  const float* proj_b = (const float*)d_in[9];
  const float* n1w    = (const float*)d_in[10];
  const float* n1b    = (const float*)d_in[11];
  const float* fc1_w  = (const float*)d_in[12];
  const float* fc1_b  = (const float*)d_in[13];
  const float* fc2_w  = (const float*)d_in[14];
  const float* fc2_b  = (const float*)d_in[15];
  const float* n2w    = (const float*)d_in[16];
  const float* n2b    = (const float*)d_in[17];
  float* out = (float*)d_out;

  // enable 128KB dynamic LDS for the 8-phase kernels (fallback to 128^2 path on failure)
  static int attr_ok = -1;
  if (attr_ok < 0) {
    hipError_t e1 = hipFuncSetAttribute(
        reinterpret_cast<const void*>(&gemm8p<1, BIAS_QKV, ACT_NONE>),
        hipFuncAttributeMaxDynamicSharedMemorySize, 131072);
    hipError_t e2 = hipFuncSetAttribute(
        reinterpret_cast<const void*>(&gemm8p<0, BIAS_SIMPLE, ACT_NONE>),
        hipFuncAttributeMaxDynamicSharedMemorySize, 131072);
    hipError_t e3 = hipFuncSetAttribute(
        reinterpret_cast<const void*>(&gemm8p<0, BIAS_SIMPLE, ACT_GELU>),
        hipFuncAttributeMaxDynamicSharedMemorySize, 131072);
    attr_ok = (e1 == hipSuccess && e2 == hipSuccess && e3 == hipSuccess) ? 1 : 0;
  }

  char* ws = (char*)d_ws;
  bf16*  QKV  = (bf16*)(ws);                          // [8192,3072]
  bf16*  H    = (bf16*)(ws);                          // [8192,4096]
  bf16*  ATT  = (bf16*)(ws + 67108864);               // [8192,1024]
  bf16*  XSB  = (bf16*)(ws + 67108864);               // [8192,1024]
  bf16*  F2   = (bf16*)(ws + 67108864);               // [8192,1024]
  bf16*  XBF  = (bf16*)(ws + 83886080);               // [8192,1024]
  bf16*  PROJ = (bf16*)(ws + 83886080);               // [8192,1024]
  float* TBL  = (float*)(ws + 100663296);             // [16,225] f32

  const bool persist = ws_size >= (size_t)125845504;  // 120 MB
  bf16* WQKV, *WPROJ, *WF1, *WF2;
  if (persist) {
    WQKV  = (bf16*)(ws + 100679680);
    WPROJ = (bf16*)(ws + 106971136);
    WF1   = (bf16*)(ws + 109068288);
    WF2   = (bf16*)(ws + 117456896);
  } else {
    WQKV  = (bf16*)(ws + 67108864);
    WPROJ = (bf16*)(ws + 50331648);
    WF1   = (bf16*)(ws + 83886080);
    WF2   = (bf16*)(ws + 83886080 + 8388608);
  }

  cpb_kernel<<<225, 512, 0, stream>>>(cpb_w1, cpb_b1, cpb_w2, TBL);
  if (persist) {
    cvt_bf16<<<1536, 256, 0, stream>>>(qkv_w, WQKV, 3145728);
    cvt_bf16<<<512, 256, 0, stream>>>(proj_w, WPROJ, 1048576);
    cvt_bf16<<<2048, 256, 0, stream>>>(fc1_w, WF1, 4194304);
    cvt_bf16<<<2048, 256, 0, stream>>>(fc2_w, WF2, 4194304);
  }

  for (int ch = 0; ch < 4; ++ch) {
    const size_t tokBase = (size_t)ch * 8192;
    const float* x_c = x + tokBase * 1024;
    float* out_c = out + tokBase * 1024;

    cvt_bf16<<<4096, 256, 0, stream>>>(x_c, XBF, 8388608);
    if (!persist) {
      cvt_bf16<<<1536, 256, 0, stream>>>(qkv_w, WQKV, 3145728);
      cvt_bf16<<<512, 256, 0, stream>>>(proj_w, WPROJ, 1048576);
    }

    if (attr_ok) {
      gemm8p<1, BIAS_QKV, ACT_NONE><<<dim3(32, 12), 512, 131072, stream>>>(
          (const unsigned short*)XBF, (const unsigned short*)WQKV,
          q_bias, v_bias, QKV, 8192, 3072, 1024);
    } else {
      gemm_bt<1, BIAS_QKV, ACT_NONE><<<dim3(64, 24), 256, 0, stream>>>(
          (const unsigned short*)XBF, (const unsigned short*)WQKV,
          q_bias, v_bias, QKV, 8192, 3072, 1024);
    }
    attn_mfma<<<512, 256, 0, stream>>>(QKV, TBL, lscale, ATT);
    if (attr_ok) {
      gemm8p<0, BIAS_SIMPLE, ACT_NONE><<<dim3(32, 4), 512, 131072, stream>>>(
          (const unsigned short*)ATT, (const unsigned short*)WPROJ,
          proj_b, nullptr, PROJ, 8192, 1024, 1024);
    } else {
      gemm_bt<0, BIAS_SIMPLE, ACT_NONE><<<dim3(64, 8), 256, 0, stream>>>(
          (const unsigned short*)ATT, (const unsigned short*)WPROJ,
          proj_b, nullptr, PROJ, 8192, 1024, 1024);
    }
    ln_residual<true, true><<<2048, 256, 0, stream>>>(PROJ, x_c, n1w, n1b, out_c, XSB);
    if (!persist) {
      cvt_bf16<<<2048, 256, 0, stream>>>(fc1_w, WF1, 4194304);
      cvt_bf16<<<2048, 256, 0, stream>>>(fc2_w, WF2, 4194304);
    }
    if (attr_ok) {
      gemm8p<0, BIAS_SIMPLE, ACT_GELU><<<dim3(32, 16), 512, 131072, stream>>>(
          (const unsigned short*)XSB, (const unsigned short*)WF1,
          fc1_b, nullptr, H, 8192, 4096, 1024);
      gemm8p<0, BIAS_SIMPLE, ACT_NONE><<<dim3(32, 4), 512, 131072, stream>>>(
          (const unsigned short*)H, (const unsigned short*)WF2,
          fc2_b, nullptr, F2, 8192, 1024, 4096);
    } else {
      gemm_bt<0, BIAS_SIMPLE, ACT_GELU><<<dim3(64, 32), 256, 0, stream>>>(
          (const unsigned short*)XSB, (const unsigned short*)WF1,
          fc1_b, nullptr, H, 8192, 4096, 1024);
      gemm_bt<0, BIAS_SIMPLE, ACT_NONE><<<dim3(64, 8), 256, 0, stream>>>(
          (const unsigned short*)H, (const unsigned short*)WF2,
          fc2_b, nullptr, F2, 8192, 1024, 4096);
    }
    ln_residual<false, false><<<2048, 256, 0, stream>>>(F2, out_c, n2w, n2b, out_c, nullptr);
  }
}

// Round 5
// 1712.596 us; speedup vs baseline: 1.0072x; 1.0072x over previous
//
#include <hip/hip_runtime.h>
#include <hip/hip_bf16.h>
#include <math.h>

typedef __hip_bfloat16 bf16;
typedef __attribute__((ext_vector_type(8))) short short8;
typedef __attribute__((ext_vector_type(4))) short short4v;
typedef __attribute__((ext_vector_type(4))) float floatx4;
typedef __attribute__((ext_vector_type(2))) unsigned int uint2v;

#define DEV static __device__ __forceinline__

DEV float bf2f(unsigned short u) {
  union { unsigned int i; float f; } x;
  x.i = ((unsigned int)u) << 16;
  return x.f;
}
DEV unsigned short f2bf_bits(float f) {
  union { bf16 h; unsigned short u; } x;
  x.h = __float2bfloat16(f);
  return x.u;
}
DEV short8 cvt8(float4 a, float4 b) {
  short8 r;
  r[0] = (short)f2bf_bits(a.x); r[1] = (short)f2bf_bits(a.y);
  r[2] = (short)f2bf_bits(a.z); r[3] = (short)f2bf_bits(a.w);
  r[4] = (short)f2bf_bits(b.x); r[5] = (short)f2bf_bits(b.y);
  r[6] = (short)f2bf_bits(b.z); r[7] = (short)f2bf_bits(b.w);
  return r;
}

// tanh-form GELU: v * sigmoid(1.5957691*v + 0.0713548*v^3). |err| vs exact ~1e-3.
DEV float gelu_fast(float v) {
  float y = v * (1.5957691216f + 0.0713548163f * v * v);
  return __fdividef(v, 1.f + __expf(-y));
}

// async global->LDS, 16B per lane. LDS dest must be wave-uniform base + lane*16.
DEV void gload_lds16(const unsigned short* g, unsigned short* l) {
  __builtin_amdgcn_global_load_lds((const __attribute__((address_space(1))) void*)g,
                                   (__attribute__((address_space(3))) void*)l,
                                   16, 0, 0);
}

// generic shared pointer -> 32-bit LDS byte offset (for asm ds_read)
DEV unsigned lds_addr(const void* p) {
  return (unsigned)(unsigned long long)(const __attribute__((address_space(3))) char*)p;
}

// window-gather (chunk-local): window-row -> source row (fuses roll(-4,-4)+partition)
DEV int gather_win_row(int wr) {
  int bw = wr >> 6, n = wr & 63;
  int bt = bw >> 2, w2 = bw & 3;
  int wi = w2 >> 1, wj = w2 & 1;
  int r = n >> 3, c = n & 7;
  int sr = (wi * 8 + r + 4) & 15;
  int sc = (wj * 8 + c + 4) & 15;
  return bt * 256 + sr * 16 + sc;
}

enum { BIAS_SIMPLE = 0, BIAS_QKV = 1 };
enum { ACT_NONE = 0, ACT_GELU = 1 };

// f32 -> bf16 bulk convert, 8 elems/thread.
__global__ __launch_bounds__(256) void cvt_bf16(const float* __restrict__ in,
                                                bf16* __restrict__ out, int n) {
  int i = (blockIdx.x * 256 + threadIdx.x) * 8;
  if (i >= n) return;
  float4 a = *reinterpret_cast<const float4*>(in + i);
  float4 b = *reinterpret_cast<const float4*>(in + i + 4);
  *reinterpret_cast<short8*>((unsigned short*)out + i) = cvt8(a, b);
}

// ====================== 256x256 8-phase GEMM (m201-faithful) ================
// BM=BN=256, BK=64, 512 thr = 8 waves (2M x 4N), per-wave 128x64.
// LDS 128KB dyn: 2 buf x {A(2 ks-chunks), B(2 ks-chunks)} of [256 rows][32 col]
// bf16 (16KB). Slot XOR (slot ^= (row>>1)&3) on BOTH stage-source and read
// address (involution, rule 21) -> 2 lanes/bank-quad = conflict-free.
// Phase = {asm ds_read frags; stage 1 chunk; [vmcnt(4) at phases 2,4 only];
// s_barrier; lgkmcnt(0)+sched_barrier(0); setprio1 16xMFMA setprio0; s_barrier}.
// Each chunk is staged 4 phases before first consume -> vmcnt(4) (= 2 chunks
// in flight) suffices; never vmcnt(0) in the main loop.
#define VMCNT(N_) asm volatile("s_waitcnt vmcnt(" #N_ ")" ::: "memory")
#define WAITLGKM() do { asm volatile("s_waitcnt lgkmcnt(0)" ::: "memory"); \
                        __builtin_amdgcn_sched_barrier(0); } while (0)
#define BARRIER() __builtin_amdgcn_s_barrier()
#define DSR(dst, addr, OFF) \
  asm volatile("ds_read_b128 %0, %1 offset:" #OFF : "=v"(dst) : "v"(addr) : "memory")

#define STG8(BUF, ISB, KS, KT) do { \
    unsigned short* d_ = (unsigned short*)(smem + (BUF) * 65536 + (ISB) * 32768 + (KS) * 16384); \
    gload_lds16(((ISB) ? bgp[0] : agp[0]) + (KT) * 64 + (KS) * 32, d_ + tid * 8); \
    gload_lds16(((ISB) ? bgp[1] : agp[1]) + (KT) * 64 + (KS) * 32, d_ + 4096 + tid * 8); \
  } while (0)

#define RD_A8(CUR, KS, IH) do { \
    unsigned a_ = smemBase + (CUR) * 65536 + (KS) * 16384 + aB0 + (IH) * 4096; \
    DSR(af[0], a_, 0); DSR(af[1], a_, 1024); DSR(af[2], a_, 2048); DSR(af[3], a_, 3072); \
  } while (0)

#define RD_B8(CUR, KS) do { \
    unsigned b_ = smemBase + (CUR) * 65536 + 32768 + (KS) * 16384 + bB0; \
    DSR(bfr[0], b_, 0); DSR(bfr[1], b_, 1024); DSR(bfr[2], b_, 2048); DSR(bfr[3], b_, 3072); \
  } while (0)

#define MFMA16(IH) do { \
    __builtin_amdgcn_s_setprio(1); \
    _Pragma("unroll") \
    for (int i_ = 0; i_ < 4; ++i_) \
      _Pragma("unroll") \
      for (int j_ = 0; j_ < 4; ++j_) \
        acc[(IH) * 4 + i_][j_] = __builtin_amdgcn_mfma_f32_16x16x32_bf16( \
            af[i_], bfr[j_], acc[(IH) * 4 + i_][j_], 0, 0, 0); \
    __builtin_amdgcn_s_setprio(0); \
  } while (0)

template <int GATHER, int BIASMODE, int ACT>
__global__ __launch_bounds__(512, 2) void gemm8p(
    const unsigned short* __restrict__ A, const unsigned short* __restrict__ B,
    const float* __restrict__ bias0, const float* __restrict__ bias1,
    bf16* __restrict__ C, int M, int N, int K)
{
  extern __shared__ __align__(16) char smem[];
  const int tid = threadIdx.x;
  const int lane = tid & 63;
  const int wave = tid >> 6;
  const int wm = wave >> 2, wn = wave & 3;
  const int l15 = lane & 15, g = lane >> 4;
  const int xr = (l15 >> 1) & 3;

  // XCD-bijective swizzle; within an XCD chunk tileN varies fastest
  // (each XCD reads a disjoint 4-M-tile band of A + shares B via L3).
  const int gy = gridDim.y;
  const int nwg = gridDim.x * gy;
  int lin = blockIdx.y * gridDim.x + blockIdx.x;
  if ((nwg & 7) == 0) lin = (lin & 7) * (nwg >> 3) + (lin >> 3);
  const int tileM = (lin / gy) * 256;
  const int tileN = (lin % gy) * 256;

  // staging: LDS slot s holds global (row=s>>2, k-group (s&3)^((s>>3)&3))
  const unsigned short* agp[2];
  const unsigned short* bgp[2];
#pragma unroll
  for (int u = 0; u < 2; ++u) {
    int s = u * 512 + tid;
    int row = s >> 2;
    int dslot = (s & 3) ^ ((s >> 3) & 3);
    int gr = tileM + row;
    int sr = GATHER ? gather_win_row(gr) : gr;
    agp[u] = A + (size_t)sr * (size_t)K + dslot * 8;
    bgp[u] = B + (size_t)(tileN + row) * (size_t)K + dslot * 8;
  }

  const unsigned smemBase = lds_addr(smem);
  // read addr for (row R, k-group g): byte = (R*4 + (g ^ ((R>>1)&3))) * 16;
  // fragment fi adds fi*1024 (folded into the offset: immediate).
  const unsigned aB0 = (unsigned)((wm * 128 + l15) * 64 + ((g ^ xr) * 16));
  const unsigned bB0 = (unsigned)((wn * 64 + l15) * 64 + ((g ^ xr) * 16));

  floatx4 acc[8][4];
#pragma unroll
  for (int i = 0; i < 8; ++i)
#pragma unroll
    for (int j = 0; j < 4; ++j) acc[i][j] = (floatx4){0.f, 0.f, 0.f, 0.f};

  short8 af[4], bfr[4];
  const int NT = K >> 6;
  int cur = 0;

  // prologue: stage tile 0 fully, full drain once
  STG8(0, 0, 0, 0); STG8(0, 1, 0, 0); STG8(0, 0, 1, 0); STG8(0, 1, 1, 0);
  VMCNT(0);
  BARRIER();

  for (int t = 0; t < NT - 1; ++t) {
    const int nb = cur ^ 1;
    // phase 1: consume (ks0, ihalf0) + B(ks0); stage next A-ks0
    RD_B8(cur, 0); RD_A8(cur, 0, 0);
    STG8(nb, 0, 0, t + 1);
    BARRIER(); WAITLGKM(); MFMA16(0); BARRIER();
    // phase 2: consume (ks0, ihalf1); stage next B-ks0; drain prev ks1 chunks
    RD_A8(cur, 0, 1);
    STG8(nb, 1, 0, t + 1);
    VMCNT(4);
    BARRIER(); WAITLGKM(); MFMA16(1); BARRIER();
    // phase 3: consume (ks1, ihalf0) + B(ks1); stage next A-ks1
    RD_B8(cur, 1); RD_A8(cur, 1, 0);
    STG8(nb, 0, 1, t + 1);
    BARRIER(); WAITLGKM(); MFMA16(0); BARRIER();
    // phase 4: consume (ks1, ihalf1); stage next B-ks1; drain next ks0 chunks
    RD_A8(cur, 1, 1);
    STG8(nb, 1, 1, t + 1);
    VMCNT(4);
    BARRIER(); WAITLGKM(); MFMA16(1); BARRIER();
    cur = nb;
  }
  // last tile: no staging; one counted drain before ks1
  RD_B8(cur, 0); RD_A8(cur, 0, 0);
  BARRIER(); WAITLGKM(); MFMA16(0); BARRIER();
  RD_A8(cur, 0, 1);
  VMCNT(0);
  BARRIER(); WAITLGKM(); MFMA16(1); BARRIER();
  RD_B8(cur, 1); RD_A8(cur, 1, 0);
  BARRIER(); WAITLGKM(); MFMA16(0); BARRIER();
  RD_A8(cur, 1, 1);
  WAITLGKM(); MFMA16(1);

  // ---- epilogue: bias+act, two 128-row rounds through LDS, dwordx4 stores ----
  __syncthreads();
  unsigned short* sh16 = (unsigned short*)smem;
  const int q = l15;
  float bv[4];
#pragma unroll
  for (int j = 0; j < 4; ++j) {
    const int colG = tileN + wn * 64 + j * 16 + q;
    if (BIASMODE == BIAS_QKV) {
      bv[j] = (colG < 1024) ? bias0[colG] : (colG < 2048 ? 0.f : bias1[colG - 2048]);
    } else {
      bv[j] = bias0[colG];
    }
  }
#pragma unroll
  for (int h = 0; h < 2; ++h) {
    if (wm == h) {
#pragma unroll
      for (int i = 0; i < 8; ++i)
#pragma unroll
        for (int j = 0; j < 4; ++j)
#pragma unroll
          for (int r = 0; r < 4; ++r) {
            float v = acc[i][j][r] + bv[j];
            if (ACT == ACT_GELU) v = gelu_fast(v);
            sh16[(i * 16 + g * 4 + r) * 264 + wn * 64 + j * 16 + q] = f2bf_bits(v);
          }
    }
    __syncthreads();
#pragma unroll
    for (int pass = 0; pass < 8; ++pass) {
      const int idx = pass * 512 + tid;
      const int row = idx >> 5, c16 = idx & 31;
      uint4 val = *reinterpret_cast<const uint4*>(&sh16[row * 264 + c16 * 8]);
      *reinterpret_cast<uint4*>(
          (unsigned short*)C + (size_t)(tileM + h * 128 + row) * (size_t)N +
          tileN + c16 * 8) = val;
    }
    __syncthreads();
  }
}

// ============== fallback 128x128 GEMM (round-3 verified) ====================
template <int GATHER, int BIASMODE, int ACT>
__global__ __launch_bounds__(256, 2) void gemm_bt(
    const unsigned short* __restrict__ A, const unsigned short* __restrict__ B,
    const float* __restrict__ bias0, const float* __restrict__ bias1,
    bf16* __restrict__ C, int M, int N, int K)
{
  __shared__ __align__(16) unsigned short sh[128 * 136];
  unsigned short* As = sh;
  unsigned short* Bs = sh + 8192;

  const int tid = threadIdx.x;
  const int lane = tid & 63;
  const int wave = tid >> 6;
  const int waveM = wave >> 1, waveN = wave & 1;
  const int tileM = blockIdx.x * 128, tileN = blockIdx.y * 128;

  const int row0 = tid >> 3;
  const int kOff = (tid & 7) * 8;

  const unsigned short* ag[4];
  const unsigned short* bg[4];
  unsigned short* al[4];
  unsigned short* bl[4];
#pragma unroll
  for (int t = 0; t < 4; ++t) {
    int gr = tileM + row0 + 32 * t;
    int sr = GATHER ? gather_win_row(gr) : gr;
    ag[t] = A + (size_t)sr * (size_t)K + (size_t)kOff;
    bg[t] = B + (size_t)(tileN + row0 + 32 * t) * (size_t)K + (size_t)kOff;
    al[t] = &As[(row0 + 32 * t) * 64 + kOff];
    bl[t] = &Bs[(row0 + 32 * t) * 64 + kOff];
  }

  floatx4 acc[4][4];
#pragma unroll
  for (int i = 0; i < 4; ++i)
#pragma unroll
    for (int j = 0; j < 4; ++j) acc[i][j] = (floatx4){0.f, 0.f, 0.f, 0.f};

  for (int k0 = 0; k0 < K; k0 += 64) {
#pragma unroll
    for (int t = 0; t < 4; ++t) {
      gload_lds16(ag[t] + k0, al[t]);
      gload_lds16(bg[t] + k0, bl[t]);
    }
    __syncthreads();
#pragma unroll
    for (int ks = 0; ks < 2; ++ks) {
      const int kk = ks * 32 + (lane >> 4) * 8;
      short8 afv[4], bfv[4];
#pragma unroll
      for (int i = 0; i < 4; ++i)
        afv[i] = *reinterpret_cast<const short8*>(
            &As[(waveM * 64 + i * 16 + (lane & 15)) * 64 + kk]);
#pragma unroll
      for (int j = 0; j < 4; ++j)
        bfv[j] = *reinterpret_cast<const short8*>(
            &Bs[(waveN * 64 + j * 16 + (lane & 15)) * 64 + kk]);
#pragma unroll
      for (int i = 0; i < 4; ++i)
#pragma unroll
        for (int j = 0; j < 4; ++j)
          acc[i][j] = __builtin_amdgcn_mfma_f32_16x16x32_bf16(afv[i], bfv[j], acc[i][j], 0, 0, 0);
    }
    __syncthreads();
  }

#pragma unroll
  for (int j = 0; j < 4; ++j) {
    const int colL = waveN * 64 + j * 16 + (lane & 15);
    const int colG = tileN + colL;
    float bv;
    if (BIASMODE == BIAS_QKV) {
      if (colG < 1024) bv = bias0[colG];
      else if (colG < 2048) bv = 0.f;
      else bv = bias1[colG - 2048];
    } else {
      bv = bias0[colG];
    }
#pragma unroll
    for (int i = 0; i < 4; ++i) {
      const int rL = waveM * 64 + i * 16 + ((lane >> 4) * 4);
#pragma unroll
      for (int r = 0; r < 4; ++r) {
        float v = acc[i][j][r] + bv;
        if (ACT == ACT_GELU) v = gelu_fast(v);
        sh[(rL + r) * 136 + colL] = f2bf_bits(v);
      }
    }
  }
  __syncthreads();
  {
    const int rowR = tid >> 4;
    const int colR = (tid & 15) * 8;
#pragma unroll
    for (int s = 0; s < 8; ++s) {
      const int row = s * 16 + rowR;
      uint4 val = *reinterpret_cast<const uint4*>(&sh[row * 136 + colR]);
      *reinterpret_cast<uint4*>(
          (unsigned short*)C + (size_t)(tileM + row) * (size_t)N + tileN + colR) = val;
    }
  }
}

// CPB MLP: regenerate the static log-spaced coord table and run 2->512->16 MLP.
// TBL layout: [16 heads][225] f32 (head-major for wave-contiguous loads).
__global__ __launch_bounds__(512) void cpb_kernel(
    const float* __restrict__ w1, const float* __restrict__ b1,
    const float* __restrict__ w2, float* __restrict__ TBL)
{
  __shared__ float hid[512];
  const int i = blockIdx.x;   // 0..224
  const int j = threadIdx.x;  // 0..511
  const float d0 = ((float)(i / 15) - 7.f) / 7.f;
  const float d1 = ((float)(i % 15) - 7.f) / 7.f;
  const float t0 = copysignf(log2f(1.f + fabsf(d0)), d0);
  const float t1 = copysignf(log2f(1.f + fabsf(d1)), d1);
  float hv = t0 * w1[j * 2] + t1 * w1[j * 2 + 1] + b1[j];
  hid[j] = fmaxf(hv, 0.f);
  __syncthreads();
  if (j < 16) {
    float s = 0.f;
    for (int jj = 0; jj < 512; ++jj) s += w2[j * 512 + jj] * hid[jj];
    TBL[j * 225 + i] = 16.f / (1.f + expf(-s));
  }
}

// MFMA attention: one wave per (window, head); block = 1 window x 4 heads.
__global__ __launch_bounds__(256) void attn_mfma(
    const bf16* __restrict__ QKV, const float* __restrict__ TBL,
    const float* __restrict__ ls, bf16* __restrict__ ATT)
{
  __shared__ __align__(16) unsigned short Ps[4][64][72];
  __shared__ float tbs[4][226];
  __shared__ int ids[64];

  const int tid = threadIdx.x;
  const int w = tid >> 6;
  const int l = tid & 63;
  const int q = l & 15;
  const int g = l >> 4;
  const int bw = blockIdx.x >> 2;
  const int h = (blockIdx.x & 3) * 4 + w;

  const unsigned short* qkvu = (const unsigned short*)QKV;
  const size_t rbase = (size_t)(bw * 64) * 3072;

  if (tid < 64) {
    const int w2 = bw & 3, wi = w2 >> 1, wj = w2 & 1;
    const int r = tid >> 3, c = tid & 7;
    const int rr = (wi == 0) ? 0 : (r < 4 ? 1 : 2);
    const int rc = (wj == 0) ? 0 : (c < 4 ? 1 : 2);
    ids[tid] = rr * 3 + rc;
  }
#pragma unroll
  for (int i = 0; i < 4; ++i) {
    int idx = i * 64 + l;
    if (idx < 225) tbs[w][idx] = TBL[h * 225 + idx];
  }
  __syncthreads();

  short8 kf[4][2], qf[4][2];
#pragma unroll
  for (int i = 0; i < 4; ++i) {
    const unsigned short* rp = qkvu + rbase + (size_t)(16 * i + q) * 3072 + h * 64 + g * 8;
    qf[i][0] = *reinterpret_cast<const short8*>(rp);
    qf[i][1] = *reinterpret_cast<const short8*>(rp + 32);
    kf[i][0] = *reinterpret_cast<const short8*>(rp + 1024);
    kf[i][1] = *reinterpret_cast<const short8*>(rp + 1024 + 32);
  }

  float rk4[4], rq4[4];
#pragma unroll
  for (int i = 0; i < 4; ++i) {
    float sk = 0.f, sq = 0.f;
#pragma unroll
    for (int ks = 0; ks < 2; ++ks)
#pragma unroll
      for (int e = 0; e < 8; ++e) {
        float kv = bf2f((unsigned short)kf[i][ks][e]);
        float qv = bf2f((unsigned short)qf[i][ks][e]);
        sk += kv * kv; sq += qv * qv;
      }
    sk += __shfl_xor(sk, 16); sk += __shfl_xor(sk, 32);
    sq += __shfl_xor(sq, 16); sq += __shfl_xor(sq, 32);
    rk4[i] = 1.f / fmaxf(sqrtf(sk), 1e-12f);
    rq4[i] = 1.f / fmaxf(sqrtf(sq), 1e-12f);
  }
  const float scl = expf(fminf(ls[h], 4.60517019f));
  float rqs[4];
#pragma unroll
  for (int j = 0; j < 4; ++j) rqs[j] = rq4[j] * scl;

  floatx4 acc[4][4];
#pragma unroll
  for (int i = 0; i < 4; ++i)
#pragma unroll
    for (int j = 0; j < 4; ++j) acc[i][j] = (floatx4){0.f, 0.f, 0.f, 0.f};
#pragma unroll
  for (int ks = 0; ks < 2; ++ks)
#pragma unroll
    for (int i = 0; i < 4; ++i)
#pragma unroll
      for (int j = 0; j < 4; ++j)
        acc[i][j] = __builtin_amdgcn_mfma_f32_16x16x32_bf16(kf[i][ks], qf[j][ks], acc[i][j], 0, 0, 0);

  short8 vf[4][2];
  const unsigned short* vbase = qkvu + rbase + 2048 + h * 64;
#pragma unroll
  for (int jp = 0; jp < 4; ++jp)
#pragma unroll
    for (int ks = 0; ks < 2; ++ks) {
      const int m0 = ks * 32 + g * 8;
      const unsigned short* vp = vbase + 16 * jp + q;
      union { short8 v; unsigned short u[8]; } pk;
#pragma unroll
      for (int e = 0; e < 8; ++e)
        pk.u[e] = vp[(size_t)(m0 + e) * 3072];
      vf[jp][ks] = pk.v;
    }

  int idn[4], rtn[4], ctn[4];
#pragma unroll
  for (int j = 0; j < 4; ++j) {
    const int n = 16 * j + q;
    rtn[j] = n >> 3; ctn[j] = n & 7; idn[j] = ids[n];
  }
#pragma unroll
  for (int i = 0; i < 4; ++i) {
#pragma unroll
    for (int r = 0; r < 4; ++r) {
      const int m = 16 * i + 4 * g + r;
      const float rkm = __shfl(rk4[i], 4 * g + r);
      const int rm = m >> 3, cm = m & 7;
      const int idm = ids[m];
#pragma unroll
      for (int j = 0; j < 4; ++j) {
        float v = acc[i][j][r] * (rkm * rqs[j]) +
                  tbs[w][(rtn[j] - rm + 7) * 15 + (ctn[j] - cm + 7)];
        if (idm != idn[j]) v -= 100.f;
        acc[i][j][r] = v;
      }
    }
  }

  float rs4[4];
#pragma unroll
  for (int j = 0; j < 4; ++j) {
    float mx = acc[0][j][0];
#pragma unroll
    for (int i = 0; i < 4; ++i)
#pragma unroll
      for (int r = 0; r < 4; ++r) mx = fmaxf(mx, acc[i][j][r]);
    mx = fmaxf(mx, __shfl_xor(mx, 16));
    mx = fmaxf(mx, __shfl_xor(mx, 32));
    float sm = 0.f;
#pragma unroll
    for (int i = 0; i < 4; ++i)
#pragma unroll
      for (int r = 0; r < 4; ++r) {
        float e = __expf(acc[i][j][r] - mx);
        acc[i][j][r] = e; sm += e;
      }
    sm += __shfl_xor(sm, 16);
    sm += __shfl_xor(sm, 32);
    rs4[j] = 1.f / sm;
  }

#pragma unroll
  for (int j = 0; j < 4; ++j)
#pragma unroll
    for (int i = 0; i < 4; ++i) {
      uint2v pw;
      pw[0] = (unsigned int)f2bf_bits(acc[i][j][0]) |
              ((unsigned int)f2bf_bits(acc[i][j][1]) << 16);
      pw[1] = (unsigned int)f2bf_bits(acc[i][j][2]) |
              ((unsigned int)f2bf_bits(acc[i][j][3]) << 16);
      *reinterpret_cast<uint2v*>(&Ps[w][16 * j + q][16 * i + 4 * g]) = pw;
    }

  floatx4 o[4][4];
#pragma unroll
  for (int i = 0; i < 4; ++i)
#pragma unroll
    for (int j = 0; j < 4; ++j) o[i][j] = (floatx4){0.f, 0.f, 0.f, 0.f};
#pragma unroll
  for (int ks = 0; ks < 2; ++ks) {
    short8 pa[4];
#pragma unroll
    for (int i2 = 0; i2 < 4; ++i2)
      pa[i2] = *reinterpret_cast<const short8*>(&Ps[w][16 * i2 + q][ks * 32 + g * 8]);
#pragma unroll
    for (int i2 = 0; i2 < 4; ++i2)
#pragma unroll
      for (int j2 = 0; j2 < 4; ++j2)
        o[i2][j2] = __builtin_amdgcn_mfma_f32_16x16x32_bf16(pa[i2], vf[j2][ks], o[i2][j2], 0, 0, 0);
  }

  unsigned short* op = (unsigned short*)ATT + (size_t)(bw * 64) * 1024 + h * 64;
#pragma unroll
  for (int i2 = 0; i2 < 4; ++i2)
#pragma unroll
    for (int r = 0; r < 4; ++r) {
      const float rsn = __shfl(rs4[i2], 4 * g + r);
      const int row = 16 * i2 + 4 * g + r;
#pragma unroll
      for (int j2 = 0; j2 < 4; ++j2)
        op[(size_t)row * 1024 + 16 * j2 + q] = f2bf_bits(o[i2][j2][r] * rsn);
    }
}

// out[tok] = base[tok] + LN(src[maprow(tok)]). One WAVE per token, 4 tokens/block.
template <bool GATHER, bool WB>
__global__ __launch_bounds__(256) void ln_residual(
    const bf16* __restrict__ src, const float* base,
    const float* __restrict__ gw, const float* __restrict__ gb,
    float* out, bf16* __restrict__ out_bf)
{
  const int tok = blockIdx.x * 4 + (threadIdx.x >> 6);
  const int lane = threadIdx.x & 63;
  int srow;
  if (GATHER) {
    const int bt = tok >> 8, rem = tok & 255, i = rem >> 4, j = rem & 15;
    const int p = (i + 12) & 15, qq = (j + 12) & 15;
    srow = (bt * 4 + (p >> 3) * 2 + (qq >> 3)) * 64 + (p & 7) * 8 + (qq & 7);
  } else {
    srow = tok;
  }
  const unsigned short* sp = (const unsigned short*)src + (size_t)srow * 1024 + lane * 16;
  short8 lv0 = *reinterpret_cast<const short8*>(sp);
  short8 lv1 = *reinterpret_cast<const short8*>(sp + 8);
  float v[16];
  float s = 0.f, sq = 0.f;
#pragma unroll
  for (int u = 0; u < 8; ++u) {
    float f = bf2f((unsigned short)lv0[u]); v[u] = f; s += f; sq += f * f;
    float g = bf2f((unsigned short)lv1[u]); v[u + 8] = g; s += g; sq += g * g;
  }
#pragma unroll
  for (int off = 32; off > 0; off >>= 1) { s += __shfl_xor(s, off); sq += __shfl_xor(sq, off); }
  const float mean = s * (1.f / 1024.f);
  const float var = sq * (1.f / 1024.f) - mean * mean;
  const float rstd = rsqrtf(var + 1e-5f);

  const float* bp = base + (size_t)tok * 1024 + lane * 16;
  float* op = out + (size_t)tok * 1024 + lane * 16;
  unsigned short* obp = WB ? ((unsigned short*)out_bf + (size_t)tok * 1024 + lane * 16) : nullptr;
  union { short8 v; unsigned short u[8]; } ob0, ob1;
#pragma unroll
  for (int q4 = 0; q4 < 4; ++q4) {
    float4 b4 = *reinterpret_cast<const float4*>(bp + q4 * 4);
    float bl[4] = {b4.x, b4.y, b4.z, b4.w};
    float4 o4;
    float* ol = (float*)&o4;
#pragma unroll
    for (int u = 0; u < 4; ++u) {
      const int c = lane * 16 + q4 * 4 + u;
      ol[u] = bl[u] + (v[q4 * 4 + u] - mean) * rstd * gw[c] + gb[c];
      if (WB) {
        if (q4 < 2) ob0.u[q4 * 4 + u] = f2bf_bits(ol[u]);
        else ob1.u[(q4 - 2) * 4 + u] = f2bf_bits(ol[u]);
      }
    }
    *reinterpret_cast<float4*>(op + q4 * 4) = o4;
  }
  if (WB) {
    *reinterpret_cast<short8*>(obp) = ob0.v;
    *reinterpret_cast<short8*>(obp + 8) = ob1.v;
  }
}

extern "C" void kernel_launch(void* const* d_in, const int* in_sizes, int n_in,
                              void* d_out, int out_size, void* d_ws, size_t ws_size,
                              hipStream_t stream) {
  (void)in_sizes; (void)n_in; (void)out_size;
  const float* x      = (const float*)d_in[0];
  const float* qkv_w  = (const float*)d_in[1];
  const float* q_bias = (const float*)d_in[2];
  const float* v_bias = (const float*)d_in[3];
  const float* lscale = (const float*)d_in[4];
  const float* cpb_w1 = (const float*)d_in[5];
  const float* cpb_b1 = (const float*)d_in[6];
  const float* cpb_w2 = (const float*)d_in[7];
  const float* proj_w = (const float*)d_in[8];
  const float* proj_b = (const float*)d_in[9];
  const float* n1w    = (const float*)d_in[10];
  const float* n1b    = (const float*)d_in[11];
  const float* fc1_w  = (const float*)d_in[12];
  const float* fc1_b  = (const float*)d_in[13];
  const float* fc2_w  = (const float*)d_in[14];
  const float* fc2_b  = (const float*)d_in[15];
  const float* n2w    = (const float*)d_in[16];
  const float* n2b    = (const float*)d_in[17];
  float* out = (float*)d_out;

  static int attr_ok = -1;
  if (attr_ok < 0) {
    hipError_t e1 = hipFuncSetAttribute(
        reinterpret_cast<const void*>(&gemm8p<1, BIAS_QKV, ACT_NONE>),
        hipFuncAttributeMaxDynamicSharedMemorySize, 131072);
    hipError_t e2 = hipFuncSetAttribute(
        reinterpret_cast<const void*>(&gemm8p<0, BIAS_SIMPLE, ACT_NONE>),
        hipFuncAttributeMaxDynamicSharedMemorySize, 131072);
    hipError_t e3 = hipFuncSetAttribute(
        reinterpret_cast<const void*>(&gemm8p<0, BIAS_SIMPLE, ACT_GELU>),
        hipFuncAttributeMaxDynamicSharedMemorySize, 131072);
    attr_ok = (e1 == hipSuccess && e2 == hipSuccess && e3 == hipSuccess) ? 1 : 0;
  }

  char* ws = (char*)d_ws;
  bf16*  QKV  = (bf16*)(ws);                          // [8192,3072]
  bf16*  H    = (bf16*)(ws);                          // [8192,4096]
  bf16*  ATT  = (bf16*)(ws + 67108864);               // [8192,1024]
  bf16*  XSB  = (bf16*)(ws + 67108864);               // [8192,1024]
  bf16*  F2   = (bf16*)(ws + 67108864);               // [8192,1024]
  bf16*  XBF  = (bf16*)(ws + 83886080);               // [8192,1024]
  bf16*  PROJ = (bf16*)(ws + 83886080);               // [8192,1024]
  float* TBL  = (float*)(ws + 100663296);             // [16,225] f32

  const bool persist = ws_size >= (size_t)125845504;  // 120 MB
  bf16* WQKV, *WPROJ, *WF1, *WF2;
  if (persist) {
    WQKV  = (bf16*)(ws + 100679680);
    WPROJ = (bf16*)(ws + 106971136);
    WF1   = (bf16*)(ws + 109068288);
    WF2   = (bf16*)(ws + 117456896);
  } else {
    WQKV  = (bf16*)(ws + 67108864);
    WPROJ = (bf16*)(ws + 50331648);
    WF1   = (bf16*)(ws + 83886080);
    WF2   = (bf16*)(ws + 83886080 + 8388608);
  }

  cpb_kernel<<<225, 512, 0, stream>>>(cpb_w1, cpb_b1, cpb_w2, TBL);
  if (persist) {
    cvt_bf16<<<1536, 256, 0, stream>>>(qkv_w, WQKV, 3145728);
    cvt_bf16<<<512, 256, 0, stream>>>(proj_w, WPROJ, 1048576);
    cvt_bf16<<<2048, 256, 0, stream>>>(fc1_w, WF1, 4194304);
    cvt_bf16<<<2048, 256, 0, stream>>>(fc2_w, WF2, 4194304);
  }

  for (int ch = 0; ch < 4; ++ch) {
    const size_t tokBase = (size_t)ch * 8192;
    const float* x_c = x + tokBase * 1024;
    float* out_c = out + tokBase * 1024;

    cvt_bf16<<<4096, 256, 0, stream>>>(x_c, XBF, 8388608);
    if (!persist) {
      cvt_bf16<<<1536, 256, 0, stream>>>(qkv_w, WQKV, 3145728);
      cvt_bf16<<<512, 256, 0, stream>>>(proj_w, WPROJ, 1048576);
    }

    if (attr_ok) {
      gemm8p<1, BIAS_QKV, ACT_NONE><<<dim3(32, 12), 512, 131072, stream>>>(
          (const unsigned short*)XBF, (const unsigned short*)WQKV,
          q_bias, v_bias, QKV, 8192, 3072, 1024);
    } else {
      gemm_bt<1, BIAS_QKV, ACT_NONE><<<dim3(64, 24), 256, 0, stream>>>(
          (const unsigned short*)XBF, (const unsigned short*)WQKV,
          q_bias, v_bias, QKV, 8192, 3072, 1024);
    }
    attn_mfma<<<512, 256, 0, stream>>>(QKV, TBL, lscale, ATT);
    if (attr_ok) {
      gemm8p<0, BIAS_SIMPLE, ACT_NONE><<<dim3(32, 4), 512, 131072, stream>>>(
          (const unsigned short*)ATT, (const unsigned short*)WPROJ,
          proj_b, nullptr, PROJ, 8192, 1024, 1024);
    } else {
      gemm_bt<0, BIAS_SIMPLE, ACT_NONE><<<dim3(64, 8), 256, 0, stream>>>(
          (const unsigned short*)ATT, (const unsigned short*)WPROJ,
          proj_b, nullptr, PROJ, 8192, 1024, 1024);
    }
    ln_residual<true, true><<<2048, 256, 0, stream>>>(PROJ, x_c, n1w, n1b, out_c, XSB);
    if (!persist) {
      cvt_bf16<<<2048, 256, 0, stream>>>(fc1_w, WF1, 4194304);
      cvt_bf16<<<2048, 256, 0, stream>>>(fc2_w, WF2, 4194304);
    }
    if (attr_ok) {
      gemm8p<0, BIAS_SIMPLE, ACT_GELU><<<dim3(32, 16), 512, 131072, stream>>>(
          (const unsigned short*)XSB, (const unsigned short*)WF1,
          fc1_b, nullptr, H, 8192, 4096, 1024);
      gemm8p<0, BIAS_SIMPLE, ACT_NONE><<<dim3(32, 4), 512, 131072, stream>>>(
          (const unsigned short*)H, (const unsigned short*)WF2,
          fc2_b, nullptr, F2, 8192, 1024, 4096);
    } else {
      gemm_bt<0, BIAS_SIMPLE, ACT_GELU><<<dim3(64, 32), 256, 0, stream>>>(
          (const unsigned short*)XSB, (const unsigned short*)WF1,
          fc1_b, nullptr, H, 8192, 4096, 1024);
      gemm_bt<0, BIAS_SIMPLE, ACT_NONE><<<dim3(64, 8), 256, 0, stream>>>(
          (const unsigned short*)H, (const unsigned short*)WF2,
          fc2_b, nullptr, F2, 8192, 1024, 4096);
    }
    ln_residual<false, false><<<2048, 256, 0, stream>>>(F2, out_c, n2w, n2b, out_c, nullptr);
  }
}

// Round 7
// 1575.450 us; speedup vs baseline: 1.0949x; 1.0871x over previous
//
#include <hip/hip_runtime.h>
#include <hip/hip_bf16.h>
#include <math.h>

typedef __hip_bfloat16 bf16;
typedef __attribute__((ext_vector_type(8))) short short8;
typedef __attribute__((ext_vector_type(4))) short short4v;
typedef __attribute__((ext_vector_type(4))) float floatx4;
typedef __attribute__((ext_vector_type(2))) unsigned int uint2v;

#define DEV static __device__ __forceinline__

DEV float bf2f(unsigned short u) {
  union { unsigned int i; float f; } x;
  x.i = ((unsigned int)u) << 16;
  return x.f;
}
DEV unsigned short f2bf_bits(float f) {
  union { bf16 h; unsigned short u; } x;
  x.h = __float2bfloat16(f);
  return x.u;
}
DEV short8 cvt8(float4 a, float4 b) {
  short8 r;
  r[0] = (short)f2bf_bits(a.x); r[1] = (short)f2bf_bits(a.y);
  r[2] = (short)f2bf_bits(a.z); r[3] = (short)f2bf_bits(a.w);
  r[4] = (short)f2bf_bits(b.x); r[5] = (short)f2bf_bits(b.y);
  r[6] = (short)f2bf_bits(b.z); r[7] = (short)f2bf_bits(b.w);
  return r;
}

// tanh-form GELU: v * sigmoid(1.5957691*v + 0.0713548*v^3). |err| vs exact ~1e-3.
DEV float gelu_fast(float v) {
  float y = v * (1.5957691216f + 0.0713548163f * v * v);
  return __fdividef(v, 1.f + __expf(-y));
}

// async global->LDS, 16B per lane. LDS dest must be wave-uniform base + lane*16.
DEV void gload_lds16(const unsigned short* g, unsigned short* l) {
  __builtin_amdgcn_global_load_lds((const __attribute__((address_space(1))) void*)g,
                                   (__attribute__((address_space(3))) void*)l,
                                   16, 0, 0);
}

// generic shared pointer -> 32-bit LDS byte offset (for asm ds_read)
DEV unsigned lds_addr(const void* p) {
  return (unsigned)(unsigned long long)(const __attribute__((address_space(3))) char*)p;
}

// window-gather (chunk-local): window-row -> source row (fuses roll(-4,-4)+partition)
DEV int gather_win_row(int wr) {
  int bw = wr >> 6, n = wr & 63;
  int bt = bw >> 2, w2 = bw & 3;
  int wi = w2 >> 1, wj = w2 & 1;
  int r = n >> 3, c = n & 7;
  int sr = (wi * 8 + r + 4) & 15;
  int sc = (wj * 8 + c + 4) & 15;
  return bt * 256 + sr * 16 + sc;
}

enum { BIAS_SIMPLE = 0, BIAS_QKV = 1 };
enum { ACT_NONE = 0, ACT_GELU = 1 };

// f32 -> bf16 bulk convert, 8 elems/thread.
__global__ __launch_bounds__(256) void cvt_bf16(const float* __restrict__ in,
                                                bf16* __restrict__ out, int n) {
  int i = (blockIdx.x * 256 + threadIdx.x) * 8;
  if (i >= n) return;
  float4 a = *reinterpret_cast<const float4*>(in + i);
  float4 b = *reinterpret_cast<const float4*>(in + i + 4);
  *reinterpret_cast<short8*>((unsigned short*)out + i) = cvt8(a, b);
}

#define VMCNT(N_) asm volatile("s_waitcnt vmcnt(" #N_ ")" ::: "memory")
#define WAITLGKM() do { asm volatile("s_waitcnt lgkmcnt(0)" ::: "memory"); \
                        __builtin_amdgcn_sched_barrier(0); } while (0)
#define BARRIER() __builtin_amdgcn_s_barrier()
#define DSR(dst, addr, OFF) \
  asm volatile("ds_read_b128 %0, %1 offset:" #OFF : "=v"(dst) : "v"(addr) : "memory")

// ====================== 256x256 8-phase GEMM (round-5 verified) =============
// Invariant: the vmcnt guarding a chunk executes (followed by a barrier) in a
// phase BEFORE the phase whose ds_reads consume that chunk.
#define STG8(BUF, ISB, KS, KT) do { \
    unsigned short* d_ = (unsigned short*)(smem + (BUF) * 65536 + (ISB) * 32768 + (KS) * 16384); \
    gload_lds16(((ISB) ? bgp[0] : agp[0]) + (KT) * 64 + (KS) * 32, d_ + tid * 8); \
    gload_lds16(((ISB) ? bgp[1] : agp[1]) + (KT) * 64 + (KS) * 32, d_ + 4096 + tid * 8); \
  } while (0)

#define RD_A8(CUR, KS, IH) do { \
    unsigned a_ = smemBase + (CUR) * 65536 + (KS) * 16384 + aB0 + (IH) * 4096; \
    DSR(af[0], a_, 0); DSR(af[1], a_, 1024); DSR(af[2], a_, 2048); DSR(af[3], a_, 3072); \
  } while (0)

#define RD_B8(CUR, KS) do { \
    unsigned b_ = smemBase + (CUR) * 65536 + 32768 + (KS) * 16384 + bB0; \
    DSR(bfr[0], b_, 0); DSR(bfr[1], b_, 1024); DSR(bfr[2], b_, 2048); DSR(bfr[3], b_, 3072); \
  } while (0)

#define MFMA16(IH) do { \
    __builtin_amdgcn_s_setprio(1); \
    _Pragma("unroll") \
    for (int i_ = 0; i_ < 4; ++i_) \
      _Pragma("unroll") \
      for (int j_ = 0; j_ < 4; ++j_) \
        acc[(IH) * 4 + i_][j_] = __builtin_amdgcn_mfma_f32_16x16x32_bf16( \
            af[i_], bfr[j_], acc[(IH) * 4 + i_][j_], 0, 0, 0); \
    __builtin_amdgcn_s_setprio(0); \
  } while (0)

template <int GATHER, int BIASMODE, int ACT>
__global__ __launch_bounds__(512, 2) void gemm8p(
    const unsigned short* __restrict__ A, const unsigned short* __restrict__ B,
    const float* __restrict__ bias0, const float* __restrict__ bias1,
    bf16* __restrict__ C, int M, int N, int K)
{
  extern __shared__ __align__(16) char smem[];
  const int tid = threadIdx.x;
  const int lane = tid & 63;
  const int wave = tid >> 6;
  const int wm = wave >> 2, wn = wave & 3;
  const int l15 = lane & 15, g = lane >> 4;
  const int xr = (l15 >> 1) & 3;

  const int gy = gridDim.y;
  const int nwg = gridDim.x * gy;
  int lin = blockIdx.y * gridDim.x + blockIdx.x;
  if ((nwg & 7) == 0) lin = (lin & 7) * (nwg >> 3) + (lin >> 3);
  const int tileM = (lin / gy) * 256;
  const int tileN = (lin % gy) * 256;

  const unsigned short* agp[2];
  const unsigned short* bgp[2];
#pragma unroll
  for (int u = 0; u < 2; ++u) {
    int s = u * 512 + tid;
    int row = s >> 2;
    int dslot = (s & 3) ^ ((s >> 3) & 3);
    int gr = tileM + row;
    int sr = GATHER ? gather_win_row(gr) : gr;
    agp[u] = A + (size_t)sr * (size_t)K + dslot * 8;
    bgp[u] = B + (size_t)(tileN + row) * (size_t)K + dslot * 8;
  }

  const unsigned smemBase = lds_addr(smem);
  const unsigned aB0 = (unsigned)((wm * 128 + l15) * 64 + ((g ^ xr) * 16));
  const unsigned bB0 = (unsigned)((wn * 64 + l15) * 64 + ((g ^ xr) * 16));

  floatx4 acc[8][4];
#pragma unroll
  for (int i = 0; i < 8; ++i)
#pragma unroll
    for (int j = 0; j < 4; ++j) acc[i][j] = (floatx4){0.f, 0.f, 0.f, 0.f};

  short8 af[4], bfr[4];
  const int NT = K >> 6;
  int cur = 0;

  STG8(0, 0, 0, 0); STG8(0, 1, 0, 0); STG8(0, 0, 1, 0); STG8(0, 1, 1, 0);
  VMCNT(0);
  BARRIER();

  for (int t = 0; t < NT - 1; ++t) {
    const int nb = cur ^ 1;
    RD_B8(cur, 0); RD_A8(cur, 0, 0);
    STG8(nb, 0, 0, t + 1);
    BARRIER(); WAITLGKM(); MFMA16(0); BARRIER();
    RD_A8(cur, 0, 1);
    STG8(nb, 1, 0, t + 1);
    VMCNT(4);
    BARRIER(); WAITLGKM(); MFMA16(1); BARRIER();
    RD_B8(cur, 1); RD_A8(cur, 1, 0);
    STG8(nb, 0, 1, t + 1);
    BARRIER(); WAITLGKM(); MFMA16(0); BARRIER();
    RD_A8(cur, 1, 1);
    STG8(nb, 1, 1, t + 1);
    VMCNT(4);
    BARRIER(); WAITLGKM(); MFMA16(1); BARRIER();
    cur = nb;
  }
  RD_B8(cur, 0); RD_A8(cur, 0, 0);
  BARRIER(); WAITLGKM(); MFMA16(0); BARRIER();
  RD_A8(cur, 0, 1);
  VMCNT(0);
  BARRIER(); WAITLGKM(); MFMA16(1); BARRIER();
  RD_B8(cur, 1); RD_A8(cur, 1, 0);
  BARRIER(); WAITLGKM(); MFMA16(0); BARRIER();
  RD_A8(cur, 1, 1);
  WAITLGKM(); MFMA16(1);

  __syncthreads();
  unsigned short* sh16 = (unsigned short*)smem;
  const int q = l15;
  float bv[4];
#pragma unroll
  for (int j = 0; j < 4; ++j) {
    const int colG = tileN + wn * 64 + j * 16 + q;
    if (BIASMODE == BIAS_QKV) {
      bv[j] = (colG < 1024) ? bias0[colG] : (colG < 2048 ? 0.f : bias1[colG - 2048]);
    } else {
      bv[j] = bias0[colG];
    }
  }
#pragma unroll
  for (int h = 0; h < 2; ++h) {
    if (wm == h) {
#pragma unroll
      for (int i = 0; i < 8; ++i)
#pragma unroll
        for (int j = 0; j < 4; ++j)
#pragma unroll
          for (int r = 0; r < 4; ++r) {
            float v = acc[i][j][r] + bv[j];
            if (ACT == ACT_GELU) v = gelu_fast(v);
            sh16[(i * 16 + g * 4 + r) * 264 + wn * 64 + j * 16 + q] = f2bf_bits(v);
          }
    }
    __syncthreads();
#pragma unroll
    for (int pass = 0; pass < 8; ++pass) {
      const int idx = pass * 512 + tid;
      const int row = idx >> 5, c16 = idx & 31;
      uint4 val = *reinterpret_cast<const uint4*>(&sh16[row * 264 + c16 * 8]);
      *reinterpret_cast<uint4*>(
          (unsigned short*)C + (size_t)(tileM + h * 128 + row) * (size_t)N +
          tileN + c16 * 8) = val;
    }
    __syncthreads();
  }
}

// ====================== 256x128 8-phase GEMM (BN=128, guard-fixed) ==========
// Stage stream per tile: A0(2), B0(1), A1(2), B1(1) = 6 insts.
// Guards moved to p2/p4 (end-of-phase, BEFORE the reads they protect):
//   p4 vmcnt(3): retires A0,B0 of next tile (outstanding {A0,B0,A1,B1}=6 -> 3)
//     -> next p1's reads valid.
//   p2 vmcnt(3): retires A1',B1' ({A1',B1',A0'',B0''}=6 -> 3) -> p3 reads valid.
// Drain: A0/B0 guarded by final loop p4; vmcnt(0) at drain-p2 guards ks1.
#define STG_A2(BUF, KS, KT) do { \
    unsigned short* d_ = (unsigned short*)(smem + (BUF) * 49152 + (KS) * 16384); \
    gload_lds16(agp[0] + (KT) * 64 + (KS) * 32, d_ + tid * 8); \
    gload_lds16(agp[1] + (KT) * 64 + (KS) * 32, d_ + 4096 + tid * 8); \
  } while (0)

#define STG_B1(BUF, KS, KT) do { \
    unsigned short* d_ = (unsigned short*)(smem + (BUF) * 49152 + 32768 + (KS) * 8192); \
    gload_lds16(bgp0 + (KT) * 64 + (KS) * 32, d_ + tid * 8); \
  } while (0)

#define RD_A8N(CUR, KS, IH) do { \
    unsigned a_ = smemBase + (CUR) * 49152 + (KS) * 16384 + aB0 + (IH) * 4096; \
    DSR(af[0], a_, 0); DSR(af[1], a_, 1024); DSR(af[2], a_, 2048); DSR(af[3], a_, 3072); \
  } while (0)

#define RD_B2N(CUR, KS) do { \
    unsigned b_ = smemBase + (CUR) * 49152 + 32768 + (KS) * 8192 + bB0; \
    DSR(bfr[0], b_, 0); DSR(bfr[1], b_, 1024); \
  } while (0)

#define MFMA8(IH) do { \
    __builtin_amdgcn_s_setprio(1); \
    _Pragma("unroll") \
    for (int i_ = 0; i_ < 4; ++i_) \
      _Pragma("unroll") \
      for (int j_ = 0; j_ < 2; ++j_) \
        acc[(IH) * 4 + i_][j_] = __builtin_amdgcn_mfma_f32_16x16x32_bf16( \
            af[i_], bfr[j_], acc[(IH) * 4 + i_][j_], 0, 0, 0); \
    __builtin_amdgcn_s_setprio(0); \
  } while (0)

template <int GATHER, int BIASMODE, int ACT>
__global__ __launch_bounds__(512, 2) void gemm8pn(
    const unsigned short* __restrict__ A, const unsigned short* __restrict__ B,
    const float* __restrict__ bias0, const float* __restrict__ bias1,
    bf16* __restrict__ C, int M, int N, int K)
{
  extern __shared__ __align__(16) char smem[];
  const int tid = threadIdx.x;
  const int lane = tid & 63;
  const int wave = tid >> 6;
  const int wm = wave >> 2, wn = wave & 3;
  const int l15 = lane & 15, g = lane >> 4;
  const int xr = (l15 >> 1) & 3;

  const int gy = gridDim.y;
  const int nwg = gridDim.x * gy;
  int lin = blockIdx.y * gridDim.x + blockIdx.x;
  if ((nwg & 7) == 0) lin = (lin & 7) * (nwg >> 3) + (lin >> 3);
  const int tileM = (lin / gy) * 256;
  const int tileN = (lin % gy) * 128;

  const unsigned short* agp[2];
#pragma unroll
  for (int u = 0; u < 2; ++u) {
    int s = u * 512 + tid;
    int row = s >> 2;
    int dslot = (s & 3) ^ ((s >> 3) & 3);
    int gr = tileM + row;
    int sr = GATHER ? gather_win_row(gr) : gr;
    agp[u] = A + (size_t)sr * (size_t)K + dslot * 8;
  }
  const unsigned short* bgp0 =
      B + (size_t)(tileN + (tid >> 2)) * (size_t)K + ((tid & 3) ^ ((tid >> 3) & 3)) * 8;

  const unsigned smemBase = lds_addr(smem);
  const unsigned aB0 = (unsigned)((wm * 128 + l15) * 64 + ((g ^ xr) * 16));
  const unsigned bB0 = (unsigned)((wn * 32 + l15) * 64 + ((g ^ xr) * 16));

  floatx4 acc[8][2];
#pragma unroll
  for (int i = 0; i < 8; ++i)
#pragma unroll
    for (int j = 0; j < 2; ++j) acc[i][j] = (floatx4){0.f, 0.f, 0.f, 0.f};

  short8 af[4], bfr[2];
  const int NT = K >> 6;
  int cur = 0;

  // prologue: stage tile 0 fully, drain
  STG_A2(0, 0, 0); STG_B1(0, 0, 0); STG_A2(0, 1, 0); STG_B1(0, 1, 0);
  VMCNT(0);
  BARRIER();

  for (int t = 0; t < NT - 1; ++t) {
    const int nb = cur ^ 1;
    // p1: consume (ks0, i0-3)+B(ks0) [guarded by prev p4]; stage next A-ks0
    RD_B2N(cur, 0); RD_A8N(cur, 0, 0);
    STG_A2(nb, 0, t + 1);
    BARRIER(); WAITLGKM(); MFMA8(0); BARRIER();
    // p2: consume (ks0, i4-7); stage next B-ks0; GUARD ks1 chunks for p3
    RD_A8N(cur, 0, 1);
    STG_B1(nb, 0, t + 1);
    VMCNT(3);
    BARRIER(); WAITLGKM(); MFMA8(1); BARRIER();
    // p3: consume (ks1, i0-3)+B(ks1) [guarded by p2]; stage next A-ks1
    RD_B2N(cur, 1); RD_A8N(cur, 1, 0);
    STG_A2(nb, 1, t + 1);
    BARRIER(); WAITLGKM(); MFMA8(0); BARRIER();
    // p4: consume (ks1, i4-7); stage next B-ks1; GUARD next tile's ks0 for p1
    RD_A8N(cur, 1, 1);
    STG_B1(nb, 1, t + 1);
    VMCNT(3);
    BARRIER(); WAITLGKM(); MFMA8(1); BARRIER();
    cur = nb;
  }
  // drain tile: A0/B0 already guarded by the final loop p4's vmcnt(3)
  RD_B2N(cur, 0); RD_A8N(cur, 0, 0);
  BARRIER(); WAITLGKM(); MFMA8(0); BARRIER();
  RD_A8N(cur, 0, 1);
  VMCNT(0);
  BARRIER(); WAITLGKM(); MFMA8(1); BARRIER();
  RD_B2N(cur, 1); RD_A8N(cur, 1, 0);
  BARRIER(); WAITLGKM(); MFMA8(0); BARRIER();
  RD_A8N(cur, 1, 1);
  WAITLGKM(); MFMA8(1);

  // epilogue: 256x128 tile, two 128-row rounds via LDS ([128][136])
  __syncthreads();
  unsigned short* sh16 = (unsigned short*)smem;
  const int q = l15;
  float bv[2];
#pragma unroll
  for (int j = 0; j < 2; ++j) {
    const int colG = tileN + wn * 32 + j * 16 + q;
    if (BIASMODE == BIAS_QKV) {
      bv[j] = (colG < 1024) ? bias0[colG] : (colG < 2048 ? 0.f : bias1[colG - 2048]);
    } else {
      bv[j] = bias0[colG];
    }
  }
#pragma unroll
  for (int h = 0; h < 2; ++h) {
    if (wm == h) {
#pragma unroll
      for (int i = 0; i < 8; ++i)
#pragma unroll
        for (int j = 0; j < 2; ++j)
#pragma unroll
          for (int r = 0; r < 4; ++r) {
            float v = acc[i][j][r] + bv[j];
            if (ACT == ACT_GELU) v = gelu_fast(v);
            sh16[(i * 16 + g * 4 + r) * 136 + wn * 32 + j * 16 + q] = f2bf_bits(v);
          }
    }
    __syncthreads();
#pragma unroll
    for (int pass = 0; pass < 4; ++pass) {
      const int idx = pass * 512 + tid;
      const int row = idx >> 4, c16 = idx & 15;
      uint4 val = *reinterpret_cast<const uint4*>(&sh16[row * 136 + c16 * 8]);
      *reinterpret_cast<uint4*>(
          (unsigned short*)C + (size_t)(tileM + h * 128 + row) * (size_t)N +
          tileN + c16 * 8) = val;
    }
    __syncthreads();
  }
}

// ============== fallback 128x128 GEMM (round-3 verified) ====================
template <int GATHER, int BIASMODE, int ACT>
__global__ __launch_bounds__(256, 2) void gemm_bt(
    const unsigned short* __restrict__ A, const unsigned short* __restrict__ B,
    const float* __restrict__ bias0, const float* __restrict__ bias1,
    bf16* __restrict__ C, int M, int N, int K)
{
  __shared__ __align__(16) unsigned short sh[128 * 136];
  unsigned short* As = sh;
  unsigned short* Bs = sh + 8192;

  const int tid = threadIdx.x;
  const int lane = tid & 63;
  const int wave = tid >> 6;
  const int waveM = wave >> 1, waveN = wave & 1;
  const int tileM = blockIdx.x * 128, tileN = blockIdx.y * 128;

  const int row0 = tid >> 3;
  const int kOff = (tid & 7) * 8;

  const unsigned short* ag[4];
  const unsigned short* bg[4];
  unsigned short* al[4];
  unsigned short* bl[4];
#pragma unroll
  for (int t = 0; t < 4; ++t) {
    int gr = tileM + row0 + 32 * t;
    int sr = GATHER ? gather_win_row(gr) : gr;
    ag[t] = A + (size_t)sr * (size_t)K + (size_t)kOff;
    bg[t] = B + (size_t)(tileN + row0 + 32 * t) * (size_t)K + (size_t)kOff;
    al[t] = &As[(row0 + 32 * t) * 64 + kOff];
    bl[t] = &Bs[(row0 + 32 * t) * 64 + kOff];
  }

  floatx4 acc[4][4];
#pragma unroll
  for (int i = 0; i < 4; ++i)
#pragma unroll
    for (int j = 0; j < 4; ++j) acc[i][j] = (floatx4){0.f, 0.f, 0.f, 0.f};

  for (int k0 = 0; k0 < K; k0 += 64) {
#pragma unroll
    for (int t = 0; t < 4; ++t) {
      gload_lds16(ag[t] + k0, al[t]);
      gload_lds16(bg[t] + k0, bl[t]);
    }
    __syncthreads();
#pragma unroll
    for (int ks = 0; ks < 2; ++ks) {
      const int kk = ks * 32 + (lane >> 4) * 8;
      short8 afv[4], bfv[4];
#pragma unroll
      for (int i = 0; i < 4; ++i)
        afv[i] = *reinterpret_cast<const short8*>(
            &As[(waveM * 64 + i * 16 + (lane & 15)) * 64 + kk]);
#pragma unroll
      for (int j = 0; j < 4; ++j)
        bfv[j] = *reinterpret_cast<const short8*>(
            &Bs[(waveN * 64 + j * 16 + (lane & 15)) * 64 + kk]);
#pragma unroll
      for (int i = 0; i < 4; ++i)
#pragma unroll
        for (int j = 0; j < 4; ++j)
          acc[i][j] = __builtin_amdgcn_mfma_f32_16x16x32_bf16(afv[i], bfv[j], acc[i][j], 0, 0, 0);
    }
    __syncthreads();
  }

#pragma unroll
  for (int j = 0; j < 4; ++j) {
    const int colL = waveN * 64 + j * 16 + (lane & 15);
    const int colG = tileN + colL;
    float bv;
    if (BIASMODE == BIAS_QKV) {
      if (colG < 1024) bv = bias0[colG];
      else if (colG < 2048) bv = 0.f;
      else bv = bias1[colG - 2048];
    } else {
      bv = bias0[colG];
    }
#pragma unroll
    for (int i = 0; i < 4; ++i) {
      const int rL = waveM * 64 + i * 16 + ((lane >> 4) * 4);
#pragma unroll
      for (int r = 0; r < 4; ++r) {
        float v = acc[i][j][r] + bv;
        if (ACT == ACT_GELU) v = gelu_fast(v);
        sh[(rL + r) * 136 + colL] = f2bf_bits(v);
      }
    }
  }
  __syncthreads();
  {
    const int rowR = tid >> 4;
    const int colR = (tid & 15) * 8;
#pragma unroll
    for (int s = 0; s < 8; ++s) {
      const int row = s * 16 + rowR;
      uint4 val = *reinterpret_cast<const uint4*>(&sh[row * 136 + colR]);
      *reinterpret_cast<uint4*>(
          (unsigned short*)C + (size_t)(tileM + row) * (size_t)N + tileN + colR) = val;
    }
  }
}

// CPB MLP: regenerate the static log-spaced coord table and run 2->512->16 MLP.
// TBL layout: [16 heads][225] f32 (head-major for wave-contiguous loads).
__global__ __launch_bounds__(512) void cpb_kernel(
    const float* __restrict__ w1, const float* __restrict__ b1,
    const float* __restrict__ w2, float* __restrict__ TBL)
{
  __shared__ float hid[512];
  const int i = blockIdx.x;   // 0..224
  const int j = threadIdx.x;  // 0..511
  const float d0 = ((float)(i / 15) - 7.f) / 7.f;
  const float d1 = ((float)(i % 15) - 7.f) / 7.f;
  const float t0 = copysignf(log2f(1.f + fabsf(d0)), d0);
  const float t1 = copysignf(log2f(1.f + fabsf(d1)), d1);
  float hv = t0 * w1[j * 2] + t1 * w1[j * 2 + 1] + b1[j];
  hid[j] = fmaxf(hv, 0.f);
  __syncthreads();
  if (j < 16) {
    float s = 0.f;
    for (int jj = 0; jj < 512; ++jj) s += w2[j * 512 + jj] * hid[jj];
    TBL[j * 225 + i] = 16.f / (1.f + expf(-s));
  }
}

// MFMA attention: one wave per (window, head); block = 1 window x 4 heads.
__global__ __launch_bounds__(256) void attn_mfma(
    const bf16* __restrict__ QKV, const float* __restrict__ TBL,
    const float* __restrict__ ls, bf16* __restrict__ ATT)
{
  __shared__ __align__(16) unsigned short Ps[4][64][72];
  __shared__ float tbs[4][226];
  __shared__ int ids[64];

  const int tid = threadIdx.x;
  const int w = tid >> 6;
  const int l = tid & 63;
  const int q = l & 15;
  const int g = l >> 4;
  const int bw = blockIdx.x >> 2;
  const int h = (blockIdx.x & 3) * 4 + w;

  const unsigned short* qkvu = (const unsigned short*)QKV;
  const size_t rbase = (size_t)(bw * 64) * 3072;

  if (tid < 64) {
    const int w2 = bw & 3, wi = w2 >> 1, wj = w2 & 1;
    const int r = tid >> 3, c = tid & 7;
    const int rr = (wi == 0) ? 0 : (r < 4 ? 1 : 2);
    const int rc = (wj == 0) ? 0 : (c < 4 ? 1 : 2);
    ids[tid] = rr * 3 + rc;
  }
#pragma unroll
  for (int i = 0; i < 4; ++i) {
    int idx = i * 64 + l;
    if (idx < 225) tbs[w][idx] = TBL[h * 225 + idx];
  }
  __syncthreads();

  short8 kf[4][2], qf[4][2];
#pragma unroll
  for (int i = 0; i < 4; ++i) {
    const unsigned short* rp = qkvu + rbase + (size_t)(16 * i + q) * 3072 + h * 64 + g * 8;
    qf[i][0] = *reinterpret_cast<const short8*>(rp);
    qf[i][1] = *reinterpret_cast<const short8*>(rp + 32);
    kf[i][0] = *reinterpret_cast<const short8*>(rp + 1024);
    kf[i][1] = *reinterpret_cast<const short8*>(rp + 1024 + 32);
  }

  float rk4[4], rq4[4];
#pragma unroll
  for (int i = 0; i < 4; ++i) {
    float sk = 0.f, sq = 0.f;
#pragma unroll
    for (int ks = 0; ks < 2; ++ks)
#pragma unroll
      for (int e = 0; e < 8; ++e) {
        float kv = bf2f((unsigned short)kf[i][ks][e]);
        float qv = bf2f((unsigned short)qf[i][ks][e]);
        sk += kv * kv; sq += qv * qv;
      }
    sk += __shfl_xor(sk, 16); sk += __shfl_xor(sk, 32);
    sq += __shfl_xor(sq, 16); sq += __shfl_xor(sq, 32);
    rk4[i] = 1.f / fmaxf(sqrtf(sk), 1e-12f);
    rq4[i] = 1.f / fmaxf(sqrtf(sq), 1e-12f);
  }
  const float scl = expf(fminf(ls[h], 4.60517019f));
  float rqs[4];
#pragma unroll
  for (int j = 0; j < 4; ++j) rqs[j] = rq4[j] * scl;

  floatx4 acc[4][4];
#pragma unroll
  for (int i = 0; i < 4; ++i)
#pragma unroll
    for (int j = 0; j < 4; ++j) acc[i][j] = (floatx4){0.f, 0.f, 0.f, 0.f};
#pragma unroll
  for (int ks = 0; ks < 2; ++ks)
#pragma unroll
    for (int i = 0; i < 4; ++i)
#pragma unroll
      for (int j = 0; j < 4; ++j)
        acc[i][j] = __builtin_amdgcn_mfma_f32_16x16x32_bf16(kf[i][ks], qf[j][ks], acc[i][j], 0, 0, 0);

  short8 vf[4][2];
  const unsigned short* vbase = qkvu + rbase + 2048 + h * 64;
#pragma unroll
  for (int jp = 0; jp < 4; ++jp)
#pragma unroll
    for (int ks = 0; ks < 2; ++ks) {
      const int m0 = ks * 32 + g * 8;
      const unsigned short* vp = vbase + 16 * jp + q;
      union { short8 v; unsigned short u[8]; } pk;
#pragma unroll
      for (int e = 0; e < 8; ++e)
        pk.u[e] = vp[(size_t)(m0 + e) * 3072];
      vf[jp][ks] = pk.v;
    }

  int idn[4], rtn[4], ctn[4];
#pragma unroll
  for (int j = 0; j < 4; ++j) {
    const int n = 16 * j + q;
    rtn[j] = n >> 3; ctn[j] = n & 7; idn[j] = ids[n];
  }
#pragma unroll
  for (int i = 0; i < 4; ++i) {
#pragma unroll
    for (int r = 0; r < 4; ++r) {
      const int m = 16 * i + 4 * g + r;
      const float rkm = __shfl(rk4[i], 4 * g + r);
      const int rm = m >> 3, cm = m & 7;
      const int idm = ids[m];
#pragma unroll
      for (int j = 0; j < 4; ++j) {
        float v = acc[i][j][r] * (rkm * rqs[j]) +
                  tbs[w][(rtn[j] - rm + 7) * 15 + (ctn[j] - cm + 7)];
        if (idm != idn[j]) v -= 100.f;
        acc[i][j][r] = v;
      }
    }
  }

  float rs4[4];
#pragma unroll
  for (int j = 0; j < 4; ++j) {
    float mx = acc[0][j][0];
#pragma unroll
    for (int i = 0; i < 4; ++i)
#pragma unroll
      for (int r = 0; r < 4; ++r) mx = fmaxf(mx, acc[i][j][r]);
    mx = fmaxf(mx, __shfl_xor(mx, 16));
    mx = fmaxf(mx, __shfl_xor(mx, 32));
    float sm = 0.f;
#pragma unroll
    for (int i = 0; i < 4; ++i)
#pragma unroll
      for (int r = 0; r < 4; ++r) {
        float e = __expf(acc[i][j][r] - mx);
        acc[i][j][r] = e; sm += e;
      }
    sm += __shfl_xor(sm, 16);
    sm += __shfl_xor(sm, 32);
    rs4[j] = 1.f / sm;
  }

#pragma unroll
  for (int j = 0; j < 4; ++j)
#pragma unroll
    for (int i = 0; i < 4; ++i) {
      uint2v pw;
      pw[0] = (unsigned int)f2bf_bits(acc[i][j][0]) |
              ((unsigned int)f2bf_bits(acc[i][j][1]) << 16);
      pw[1] = (unsigned int)f2bf_bits(acc[i][j][2]) |
              ((unsigned int)f2bf_bits(acc[i][j][3]) << 16);
      *reinterpret_cast<uint2v*>(&Ps[w][16 * j + q][16 * i + 4 * g]) = pw;
    }

  floatx4 o[4][4];
#pragma unroll
  for (int i = 0; i < 4; ++i)
#pragma unroll
    for (int j = 0; j < 4; ++j) o[i][j] = (floatx4){0.f, 0.f, 0.f, 0.f};
#pragma unroll
  for (int ks = 0; ks < 2; ++ks) {
    short8 pa[4];
#pragma unroll
    for (int i2 = 0; i2 < 4; ++i2)
      pa[i2] = *reinterpret_cast<const short8*>(&Ps[w][16 * i2 + q][ks * 32 + g * 8]);
#pragma unroll
    for (int i2 = 0; i2 < 4; ++i2)
#pragma unroll
      for (int j2 = 0; j2 < 4; ++j2)
        o[i2][j2] = __builtin_amdgcn_mfma_f32_16x16x32_bf16(pa[i2], vf[j2][ks], o[i2][j2], 0, 0, 0);
  }

  unsigned short* op = (unsigned short*)ATT + (size_t)(bw * 64) * 1024 + h * 64;
#pragma unroll
  for (int i2 = 0; i2 < 4; ++i2)
#pragma unroll
    for (int r = 0; r < 4; ++r) {
      const float rsn = __shfl(rs4[i2], 4 * g + r);
      const int row = 16 * i2 + 4 * g + r;
#pragma unroll
      for (int j2 = 0; j2 < 4; ++j2)
        op[(size_t)row * 1024 + 16 * j2 + q] = f2bf_bits(o[i2][j2][r] * rsn);
    }
}

// out[tok] = base[tok] + LN(src[maprow(tok)]). One WAVE per token, 4 tokens/block.
template <bool GATHER, bool WB>
__global__ __launch_bounds__(256) void ln_residual(
    const bf16* __restrict__ src, const float* base,
    const float* __restrict__ gw, const float* __restrict__ gb,
    float* out, bf16* __restrict__ out_bf)
{
  const int tok = blockIdx.x * 4 + (threadIdx.x >> 6);
  const int lane = threadIdx.x & 63;
  int srow;
  if (GATHER) {
    const int bt = tok >> 8, rem = tok & 255, i = rem >> 4, j = rem & 15;
    const int p = (i + 12) & 15, qq = (j + 12) & 15;
    srow = (bt * 4 + (p >> 3) * 2 + (qq >> 3)) * 64 + (p & 7) * 8 + (qq & 7);
  } else {
    srow = tok;
  }
  const unsigned short* sp = (const unsigned short*)src + (size_t)srow * 1024 + lane * 16;
  short8 lv0 = *reinterpret_cast<const short8*>(sp);
  short8 lv1 = *reinterpret_cast<const short8*>(sp + 8);
  float v[16];
  float s = 0.f, sq = 0.f;
#pragma unroll
  for (int u = 0; u < 8; ++u) {
    float f = bf2f((unsigned short)lv0[u]); v[u] = f; s += f; sq += f * f;
    float g = bf2f((unsigned short)lv1[u]); v[u + 8] = g; s += g; sq += g * g;
  }
#pragma unroll
  for (int off = 32; off > 0; off >>= 1) { s += __shfl_xor(s, off); sq += __shfl_xor(sq, off); }
  const float mean = s * (1.f / 1024.f);
  const float var = sq * (1.f / 1024.f) - mean * mean;
  const float rstd = rsqrtf(var + 1e-5f);

  const float* bp = base + (size_t)tok * 1024 + lane * 16;
  float* op = out + (size_t)tok * 1024 + lane * 16;
  unsigned short* obp = WB ? ((unsigned short*)out_bf + (size_t)tok * 1024 + lane * 16) : nullptr;
  union { short8 v; unsigned short u[8]; } ob0, ob1;
#pragma unroll
  for (int q4 = 0; q4 < 4; ++q4) {
    float4 b4 = *reinterpret_cast<const float4*>(bp + q4 * 4);
    float bl[4] = {b4.x, b4.y, b4.z, b4.w};
    float4 o4;
    float* ol = (float*)&o4;
#pragma unroll
    for (int u = 0; u < 4; ++u) {
      const int c = lane * 16 + q4 * 4 + u;
      ol[u] = bl[u] + (v[q4 * 4 + u] - mean) * rstd * gw[c] + gb[c];
      if (WB) {
        if (q4 < 2) ob0.u[q4 * 4 + u] = f2bf_bits(ol[u]);
        else ob1.u[(q4 - 2) * 4 + u] = f2bf_bits(ol[u]);
      }
    }
    *reinterpret_cast<float4*>(op + q4 * 4) = o4;
  }
  if (WB) {
    *reinterpret_cast<short8*>(obp) = ob0.v;
    *reinterpret_cast<short8*>(obp + 8) = ob1.v;
  }
}

extern "C" void kernel_launch(void* const* d_in, const int* in_sizes, int n_in,
                              void* d_out, int out_size, void* d_ws, size_t ws_size,
                              hipStream_t stream) {
  (void)in_sizes; (void)n_in; (void)out_size;
  const float* x      = (const float*)d_in[0];
  const float* qkv_w  = (const float*)d_in[1];
  const float* q_bias = (const float*)d_in[2];
  const float* v_bias = (const float*)d_in[3];
  const float* lscale = (const float*)d_in[4];
  const float* cpb_w1 = (const float*)d_in[5];
  const float* cpb_b1 = (const float*)d_in[6];
  const float* cpb_w2 = (const float*)d_in[7];
  const float* proj_w = (const float*)d_in[8];
  const float* proj_b = (const float*)d_in[9];
  const float* n1w    = (const float*)d_in[10];
  const float* n1b    = (const float*)d_in[11];
  const float* fc1_w  = (const float*)d_in[12];
  const float* fc1_b  = (const float*)d_in[13];
  const float* fc2_w  = (const float*)d_in[14];
  const float* fc2_b  = (const float*)d_in[15];
  const float* n2w    = (const float*)d_in[16];
  const float* n2b    = (const float*)d_in[17];
  float* out = (float*)d_out;

  static int attr_ok = -1;
  if (attr_ok < 0) {
    hipError_t e1 = hipFuncSetAttribute(
        reinterpret_cast<const void*>(&gemm8p<0, BIAS_SIMPLE, ACT_GELU>),
        hipFuncAttributeMaxDynamicSharedMemorySize, 131072);
    hipError_t e2 = hipFuncSetAttribute(
        reinterpret_cast<const void*>(&gemm8pn<1, BIAS_QKV, ACT_NONE>),
        hipFuncAttributeMaxDynamicSharedMemorySize, 98304);
    hipError_t e3 = hipFuncSetAttribute(
        reinterpret_cast<const void*>(&gemm8pn<0, BIAS_SIMPLE, ACT_NONE>),
        hipFuncAttributeMaxDynamicSharedMemorySize, 98304);
    attr_ok = (e1 == hipSuccess && e2 == hipSuccess && e3 == hipSuccess) ? 1 : 0;
  }

  char* ws = (char*)d_ws;
  bf16*  QKV  = (bf16*)(ws);                          // [8192,3072]
  bf16*  H    = (bf16*)(ws);                          // [8192,4096]
  bf16*  ATT  = (bf16*)(ws + 67108864);               // [8192,1024]
  bf16*  XSB  = (bf16*)(ws + 67108864);               // [8192,1024]
  bf16*  F2   = (bf16*)(ws + 67108864);               // [8192,1024]
  bf16*  XBF  = (bf16*)(ws + 83886080);               // [8192,1024]
  bf16*  PROJ = (bf16*)(ws + 83886080);               // [8192,1024]
  float* TBL  = (float*)(ws + 100663296);             // [16,225] f32

  const bool persist = ws_size >= (size_t)125845504;  // 120 MB
  bf16* WQKV, *WPROJ, *WF1, *WF2;
  if (persist) {
    WQKV  = (bf16*)(ws + 100679680);
    WPROJ = (bf16*)(ws + 106971136);
    WF1   = (bf16*)(ws + 109068288);
    WF2   = (bf16*)(ws + 117456896);
  } else {
    WQKV  = (bf16*)(ws + 67108864);
    WPROJ = (bf16*)(ws + 50331648);
    WF1   = (bf16*)(ws + 83886080);
    WF2   = (bf16*)(ws + 83886080 + 8388608);
  }

  cpb_kernel<<<225, 512, 0, stream>>>(cpb_w1, cpb_b1, cpb_w2, TBL);
  if (persist) {
    cvt_bf16<<<1536, 256, 0, stream>>>(qkv_w, WQKV, 3145728);
    cvt_bf16<<<512, 256, 0, stream>>>(proj_w, WPROJ, 1048576);
    cvt_bf16<<<2048, 256, 0, stream>>>(fc1_w, WF1, 4194304);
    cvt_bf16<<<2048, 256, 0, stream>>>(fc2_w, WF2, 4194304);
  }

  for (int ch = 0; ch < 4; ++ch) {
    const size_t tokBase = (size_t)ch * 8192;
    const float* x_c = x + tokBase * 1024;
    float* out_c = out + tokBase * 1024;

    cvt_bf16<<<4096, 256, 0, stream>>>(x_c, XBF, 8388608);
    if (!persist) {
      cvt_bf16<<<1536, 256, 0, stream>>>(qkv_w, WQKV, 3145728);
      cvt_bf16<<<512, 256, 0, stream>>>(proj_w, WPROJ, 1048576);
    }

    if (attr_ok) {
      // N=3072: BN=128 -> 32x24 = 768 blocks = exactly 3 full CU rounds
      gemm8pn<1, BIAS_QKV, ACT_NONE><<<dim3(32, 24), 512, 98304, stream>>>(
          (const unsigned short*)XBF, (const unsigned short*)WQKV,
          q_bias, v_bias, QKV, 8192, 3072, 1024);
    } else {
      gemm_bt<1, BIAS_QKV, ACT_NONE><<<dim3(64, 24), 256, 0, stream>>>(
          (const unsigned short*)XBF, (const unsigned short*)WQKV,
          q_bias, v_bias, QKV, 8192, 3072, 1024);
    }
    attn_mfma<<<512, 256, 0, stream>>>(QKV, TBL, lscale, ATT);
    if (attr_ok) {
      // N=1024: BN=128 -> 32x8 = 256 blocks = full chip
      gemm8pn<0, BIAS_SIMPLE, ACT_NONE><<<dim3(32, 8), 512, 98304, stream>>>(
          (const unsigned short*)ATT, (const unsigned short*)WPROJ,
          proj_b, nullptr, PROJ, 8192, 1024, 1024);
    } else {
      gemm_bt<0, BIAS_SIMPLE, ACT_NONE><<<dim3(64, 8), 256, 0, stream>>>(
          (const unsigned short*)ATT, (const unsigned short*)WPROJ,
          proj_b, nullptr, PROJ, 8192, 1024, 1024);
    }
    ln_residual<true, true><<<2048, 256, 0, stream>>>(PROJ, x_c, n1w, n1b, out_c, XSB);
    if (!persist) {
      cvt_bf16<<<2048, 256, 0, stream>>>(fc1_w, WF1, 4194304);
      cvt_bf16<<<2048, 256, 0, stream>>>(fc2_w, WF2, 4194304);
    }
    if (attr_ok) {
      // N=4096: BN=256 -> 512 blocks = 2 exact full rounds
      gemm8p<0, BIAS_SIMPLE, ACT_GELU><<<dim3(32, 16), 512, 131072, stream>>>(
          (const unsigned short*)XSB, (const unsigned short*)WF1,
          fc1_b, nullptr, H, 8192, 4096, 1024);
      // N=1024, K=4096: BN=128 -> 256 blocks = full chip
      gemm8pn<0, BIAS_SIMPLE, ACT_NONE><<<dim3(32, 8), 512, 98304, stream>>>(
          (const unsigned short*)H, (const unsigned short*)WF2,
          fc2_b, nullptr, F2, 8192, 1024, 4096);
    } else {
      gemm_bt<0, BIAS_SIMPLE, ACT_GELU><<<dim3(64, 32), 256, 0, stream>>>(
          (const unsigned short*)XSB, (const unsigned short*)WF1,
          fc1_b, nullptr, H, 8192, 4096, 1024);
      gemm_bt<0, BIAS_SIMPLE, ACT_NONE><<<dim3(64, 8), 256, 0, stream>>>(
          (const unsigned short*)H, (const unsigned short*)WF2,
          fc2_b, nullptr, F2, 8192, 1024, 4096);
    }
    ln_residual<false, false><<<2048, 256, 0, stream>>>(F2, out_c, n2w, n2b, out_c, nullptr);
  }
}

// Round 8
// 1574.086 us; speedup vs baseline: 1.0958x; 1.0009x over previous
//
#include <hip/hip_runtime.h>
#include <hip/hip_bf16.h>
#include <math.h>

typedef __hip_bfloat16 bf16;
typedef __attribute__((ext_vector_type(8))) short short8;
typedef __attribute__((ext_vector_type(4))) short short4v;
typedef __attribute__((ext_vector_type(4))) float floatx4;
typedef __attribute__((ext_vector_type(2))) unsigned int uint2v;

#define DEV static __device__ __forceinline__

DEV float bf2f(unsigned short u) {
  union { unsigned int i; float f; } x;
  x.i = ((unsigned int)u) << 16;
  return x.f;
}
DEV unsigned short f2bf_bits(float f) {
  union { bf16 h; unsigned short u; } x;
  x.h = __float2bfloat16(f);
  return x.u;
}
DEV short8 cvt8(float4 a, float4 b) {
  short8 r;
  r[0] = (short)f2bf_bits(a.x); r[1] = (short)f2bf_bits(a.y);
  r[2] = (short)f2bf_bits(a.z); r[3] = (short)f2bf_bits(a.w);
  r[4] = (short)f2bf_bits(b.x); r[5] = (short)f2bf_bits(b.y);
  r[6] = (short)f2bf_bits(b.z); r[7] = (short)f2bf_bits(b.w);
  return r;
}

// tanh-form GELU: v * sigmoid(1.5957691*v + 0.0713548*v^3). |err| vs exact ~1e-3.
DEV float gelu_fast(float v) {
  float y = v * (1.5957691216f + 0.0713548163f * v * v);
  return __fdividef(v, 1.f + __expf(-y));
}

// async global->LDS, 16B per lane. LDS dest must be wave-uniform base + lane*16.
DEV void gload_lds16(const unsigned short* g, unsigned short* l) {
  __builtin_amdgcn_global_load_lds((const __attribute__((address_space(1))) void*)g,
                                   (__attribute__((address_space(3))) void*)l,
                                   16, 0, 0);
}

// generic shared pointer -> 32-bit LDS byte offset (for asm ds_read)
DEV unsigned lds_addr(const void* p) {
  return (unsigned)(unsigned long long)(const __attribute__((address_space(3))) char*)p;
}

// window-gather (chunk-local): window-row -> source row (fuses roll(-4,-4)+partition)
DEV int gather_win_row(int wr) {
  int bw = wr >> 6, n = wr & 63;
  int bt = bw >> 2, w2 = bw & 3;
  int wi = w2 >> 1, wj = w2 & 1;
  int r = n >> 3, c = n & 7;
  int sr = (wi * 8 + r + 4) & 15;
  int sc = (wj * 8 + c + 4) & 15;
  return bt * 256 + sr * 16 + sc;
}

enum { BIAS_SIMPLE = 0, BIAS_QKV = 1 };
enum { ACT_NONE = 0, ACT_GELU = 1 };

// f32 -> bf16 bulk convert, 8 elems/thread.
__global__ __launch_bounds__(256) void cvt_bf16(const float* __restrict__ in,
                                                bf16* __restrict__ out, int n) {
  int i = (blockIdx.x * 256 + threadIdx.x) * 8;
  if (i >= n) return;
  float4 a = *reinterpret_cast<const float4*>(in + i);
  float4 b = *reinterpret_cast<const float4*>(in + i + 4);
  *reinterpret_cast<short8*>((unsigned short*)out + i) = cvt8(a, b);
}

#define VMCNT(N_) asm volatile("s_waitcnt vmcnt(" #N_ ")" ::: "memory")
#define LGKM(N_) do { asm volatile("s_waitcnt lgkmcnt(" #N_ ")" ::: "memory"); \
                      __builtin_amdgcn_sched_barrier(0); } while (0)
#define BARRIER() __builtin_amdgcn_s_barrier()
#define DSR(dst, addr, OFF) \
  asm volatile("ds_read_b128 %0, %1 offset:" #OFF : "=v"(dst) : "v"(addr) : "memory")

// ====================== 256x256 8-phase GEMM (pipelined frag reads) =========
// Guard invariant (round-6/7 verified): the vmcnt guarding a chunk executes,
// followed by a barrier, BEFORE the reads that consume it. New in round 8:
// one-phase-ahead register prefetch — each phase issues the NEXT phase's
// ds_reads (alternate reg set) right after its entry barrier, then waits its
// own reads with a COUNTED lgkmcnt -> phase p+1's LDS burst overlaps phase p's
// MFMA burst. lgkm counts: retire-oldest, pure-DS in-order.
//   loop MFMA uses: p1(af0,bfr0) p2(af1,bfr0) p3(af0,bfr1) p4(af1,bfr1)
//   issues:        p1->af1(4)   p2->bfr1+af0(8) p3->af1(4) p4->nb bfr0+af0(8)
#define STG8(BUF, ISB, KS, KT) do { \
    unsigned short* d_ = (unsigned short*)(smem + (BUF) * 65536 + (ISB) * 32768 + (KS) * 16384); \
    gload_lds16(((ISB) ? bgp[0] : agp[0]) + (KT) * 64 + (KS) * 32, d_ + tid * 8); \
    gload_lds16(((ISB) ? bgp[1] : agp[1]) + (KT) * 64 + (KS) * 32, d_ + 4096 + tid * 8); \
  } while (0)

#define RD_A8S(ST, CUR, KS, IH) do { \
    unsigned a_ = smemBase + (CUR) * 65536 + (KS) * 16384 + aB0 + (IH) * 4096; \
    DSR(af[ST][0], a_, 0); DSR(af[ST][1], a_, 1024); \
    DSR(af[ST][2], a_, 2048); DSR(af[ST][3], a_, 3072); \
  } while (0)

#define RD_B8S(ST, CUR, KS) do { \
    unsigned b_ = smemBase + (CUR) * 65536 + 32768 + (KS) * 16384 + bB0; \
    DSR(bfr[ST][0], b_, 0); DSR(bfr[ST][1], b_, 1024); \
    DSR(bfr[ST][2], b_, 2048); DSR(bfr[ST][3], b_, 3072); \
  } while (0)

#define MFMA16S(IH, AS, BS) do { \
    __builtin_amdgcn_s_setprio(1); \
    _Pragma("unroll") \
    for (int i_ = 0; i_ < 4; ++i_) \
      _Pragma("unroll") \
      for (int j_ = 0; j_ < 4; ++j_) \
        acc[(IH) * 4 + i_][j_] = __builtin_amdgcn_mfma_f32_16x16x32_bf16( \
            af[AS][i_], bfr[BS][j_], acc[(IH) * 4 + i_][j_], 0, 0, 0); \
    __builtin_amdgcn_s_setprio(0); \
  } while (0)

template <int GATHER, int BIASMODE, int ACT>
__global__ __launch_bounds__(512, 2) void gemm8p(
    const unsigned short* __restrict__ A, const unsigned short* __restrict__ B,
    const float* __restrict__ bias0, const float* __restrict__ bias1,
    bf16* __restrict__ C, int M, int N, int K)
{
  extern __shared__ __align__(16) char smem[];
  const int tid = threadIdx.x;
  const int lane = tid & 63;
  const int wave = tid >> 6;
  const int wm = wave >> 2, wn = wave & 3;
  const int l15 = lane & 15, g = lane >> 4;
  const int xr = (l15 >> 1) & 3;

  const int gy = gridDim.y;
  const int nwg = gridDim.x * gy;
  int lin = blockIdx.y * gridDim.x + blockIdx.x;
  if ((nwg & 7) == 0) lin = (lin & 7) * (nwg >> 3) + (lin >> 3);
  const int tileM = (lin / gy) * 256;
  const int tileN = (lin % gy) * 256;

  const unsigned short* agp[2];
  const unsigned short* bgp[2];
#pragma unroll
  for (int u = 0; u < 2; ++u) {
    int s = u * 512 + tid;
    int row = s >> 2;
    int dslot = (s & 3) ^ ((s >> 3) & 3);
    int gr = tileM + row;
    int sr = GATHER ? gather_win_row(gr) : gr;
    agp[u] = A + (size_t)sr * (size_t)K + dslot * 8;
    bgp[u] = B + (size_t)(tileN + row) * (size_t)K + dslot * 8;
  }

  const unsigned smemBase = lds_addr(smem);
  const unsigned aB0 = (unsigned)((wm * 128 + l15) * 64 + ((g ^ xr) * 16));
  const unsigned bB0 = (unsigned)((wn * 64 + l15) * 64 + ((g ^ xr) * 16));

  floatx4 acc[8][4];
#pragma unroll
  for (int i = 0; i < 8; ++i)
#pragma unroll
    for (int j = 0; j < 4; ++j) acc[i][j] = (floatx4){0.f, 0.f, 0.f, 0.f};

  short8 af[2][4], bfr[2][4];
  const int NT = K >> 6;
  int cur = 0;

  // prologue: stage tile 0, drain, then issue p1's fragment reads (set 0)
  STG8(0, 0, 0, 0); STG8(0, 1, 0, 0); STG8(0, 0, 1, 0); STG8(0, 1, 1, 0);
  VMCNT(0);
  BARRIER();
  RD_B8S(0, 0, 0); RD_A8S(0, 0, 0, 0);   // 8 reads outstanding

  for (int t = 0; t < NT - 1; ++t) {
    const int nb = cur ^ 1;
    // p1
    STG8(nb, 0, 0, t + 1);
    BARRIER();
    RD_A8S(1, cur, 0, 1);                 // p2's af (4)
    LGKM(4); MFMA16S(0, 0, 0);
    BARRIER();
    // p2
    STG8(nb, 1, 0, t + 1);
    VMCNT(4);
    BARRIER();
    RD_B8S(1, cur, 1); RD_A8S(0, cur, 1, 0);  // p3's bfr+af (8); guarded by VMCNT above
    LGKM(8); MFMA16S(1, 1, 0);
    BARRIER();
    // p3
    STG8(nb, 0, 1, t + 1);
    BARRIER();
    RD_A8S(1, cur, 1, 1);                 // p4's af (4)
    LGKM(4); MFMA16S(0, 0, 1);
    BARRIER();
    // p4
    STG8(nb, 1, 1, t + 1);
    VMCNT(4);
    BARRIER();
    RD_B8S(0, nb, 0); RD_A8S(0, nb, 0, 0);    // next p1's (8); guarded by VMCNT above
    LGKM(8); MFMA16S(1, 1, 1);
    BARRIER();
    cur = nb;
  }
  // drain tile (p1 frags already issued by final loop p4; vm outstanding = cur ks1)
  RD_A8S(1, cur, 0, 1);
  LGKM(4); MFMA16S(0, 0, 0);
  BARRIER();
  VMCNT(0);
  BARRIER();
  RD_B8S(1, cur, 1); RD_A8S(0, cur, 1, 0);
  LGKM(8); MFMA16S(1, 1, 0);
  RD_A8S(1, cur, 1, 1);
  LGKM(4); MFMA16S(0, 0, 1);
  LGKM(0); MFMA16S(1, 1, 1);

  __syncthreads();
  unsigned short* sh16 = (unsigned short*)smem;
  const int q = l15;
  float bv[4];
#pragma unroll
  for (int j = 0; j < 4; ++j) {
    const int colG = tileN + wn * 64 + j * 16 + q;
    if (BIASMODE == BIAS_QKV) {
      bv[j] = (colG < 1024) ? bias0[colG] : (colG < 2048 ? 0.f : bias1[colG - 2048]);
    } else {
      bv[j] = bias0[colG];
    }
  }
#pragma unroll
  for (int h = 0; h < 2; ++h) {
    if (wm == h) {
#pragma unroll
      for (int i = 0; i < 8; ++i)
#pragma unroll
        for (int j = 0; j < 4; ++j)
#pragma unroll
          for (int r = 0; r < 4; ++r) {
            float v = acc[i][j][r] + bv[j];
            if (ACT == ACT_GELU) v = gelu_fast(v);
            sh16[(i * 16 + g * 4 + r) * 264 + wn * 64 + j * 16 + q] = f2bf_bits(v);
          }
    }
    __syncthreads();
#pragma unroll
    for (int pass = 0; pass < 8; ++pass) {
      const int idx = pass * 512 + tid;
      const int row = idx >> 5, c16 = idx & 31;
      uint4 val = *reinterpret_cast<const uint4*>(&sh16[row * 264 + c16 * 8]);
      *reinterpret_cast<uint4*>(
          (unsigned short*)C + (size_t)(tileM + h * 128 + row) * (size_t)N +
          tileN + c16 * 8) = val;
    }
    __syncthreads();
  }
}

// ====================== 256x128 8-phase GEMM (pipelined frag reads) =========
// Same pipelining; stage stream A0(2),B0(1),A1(2),B1(1); guards at p2/p4
// (vmcnt(3), round-7 verified). lgkm counts: p1:4 p2:6 p3:4 p4:6.
#define STG_A2(BUF, KS, KT) do { \
    unsigned short* d_ = (unsigned short*)(smem + (BUF) * 49152 + (KS) * 16384); \
    gload_lds16(agp[0] + (KT) * 64 + (KS) * 32, d_ + tid * 8); \
    gload_lds16(agp[1] + (KT) * 64 + (KS) * 32, d_ + 4096 + tid * 8); \
  } while (0)

#define STG_B1(BUF, KS, KT) do { \
    unsigned short* d_ = (unsigned short*)(smem + (BUF) * 49152 + 32768 + (KS) * 8192); \
    gload_lds16(bgp0 + (KT) * 64 + (KS) * 32, d_ + tid * 8); \
  } while (0)

#define RD_A8NS(ST, CUR, KS, IH) do { \
    unsigned a_ = smemBase + (CUR) * 49152 + (KS) * 16384 + aB0 + (IH) * 4096; \
    DSR(af[ST][0], a_, 0); DSR(af[ST][1], a_, 1024); \
    DSR(af[ST][2], a_, 2048); DSR(af[ST][3], a_, 3072); \
  } while (0)

#define RD_B2NS(ST, CUR, KS) do { \
    unsigned b_ = smemBase + (CUR) * 49152 + 32768 + (KS) * 8192 + bB0; \
    DSR(bfr[ST][0], b_, 0); DSR(bfr[ST][1], b_, 1024); \
  } while (0)

#define MFMA8S(IH, AS, BS) do { \
    __builtin_amdgcn_s_setprio(1); \
    _Pragma("unroll") \
    for (int i_ = 0; i_ < 4; ++i_) \
      _Pragma("unroll") \
      for (int j_ = 0; j_ < 2; ++j_) \
        acc[(IH) * 4 + i_][j_] = __builtin_amdgcn_mfma_f32_16x16x32_bf16( \
            af[AS][i_], bfr[BS][j_], acc[(IH) * 4 + i_][j_], 0, 0, 0); \
    __builtin_amdgcn_s_setprio(0); \
  } while (0)

template <int GATHER, int BIASMODE, int ACT>
__global__ __launch_bounds__(512, 2) void gemm8pn(
    const unsigned short* __restrict__ A, const unsigned short* __restrict__ B,
    const float* __restrict__ bias0, const float* __restrict__ bias1,
    bf16* __restrict__ C, int M, int N, int K)
{
  extern __shared__ __align__(16) char smem[];
  const int tid = threadIdx.x;
  const int lane = tid & 63;
  const int wave = tid >> 6;
  const int wm = wave >> 2, wn = wave & 3;
  const int l15 = lane & 15, g = lane >> 4;
  const int xr = (l15 >> 1) & 3;

  const int gy = gridDim.y;
  const int nwg = gridDim.x * gy;
  int lin = blockIdx.y * gridDim.x + blockIdx.x;
  if ((nwg & 7) == 0) lin = (lin & 7) * (nwg >> 3) + (lin >> 3);
  const int tileM = (lin / gy) * 256;
  const int tileN = (lin % gy) * 128;

  const unsigned short* agp[2];
#pragma unroll
  for (int u = 0; u < 2; ++u) {
    int s = u * 512 + tid;
    int row = s >> 2;
    int dslot = (s & 3) ^ ((s >> 3) & 3);
    int gr = tileM + row;
    int sr = GATHER ? gather_win_row(gr) : gr;
    agp[u] = A + (size_t)sr * (size_t)K + dslot * 8;
  }
  const unsigned short* bgp0 =
      B + (size_t)(tileN + (tid >> 2)) * (size_t)K + ((tid & 3) ^ ((tid >> 3) & 3)) * 8;

  const unsigned smemBase = lds_addr(smem);
  const unsigned aB0 = (unsigned)((wm * 128 + l15) * 64 + ((g ^ xr) * 16));
  const unsigned bB0 = (unsigned)((wn * 32 + l15) * 64 + ((g ^ xr) * 16));

  floatx4 acc[8][2];
#pragma unroll
  for (int i = 0; i < 8; ++i)
#pragma unroll
    for (int j = 0; j < 2; ++j) acc[i][j] = (floatx4){0.f, 0.f, 0.f, 0.f};

  short8 af[2][4], bfr[2][2];
  const int NT = K >> 6;
  int cur = 0;

  STG_A2(0, 0, 0); STG_B1(0, 0, 0); STG_A2(0, 1, 0); STG_B1(0, 1, 0);
  VMCNT(0);
  BARRIER();
  RD_B2NS(0, 0, 0); RD_A8NS(0, 0, 0, 0);   // 6 reads outstanding

  for (int t = 0; t < NT - 1; ++t) {
    const int nb = cur ^ 1;
    // p1
    STG_A2(nb, 0, t + 1);
    BARRIER();
    RD_A8NS(1, cur, 0, 1);                // p2's af (4)
    LGKM(4); MFMA8S(0, 0, 0);
    BARRIER();
    // p2
    STG_B1(nb, 0, t + 1);
    VMCNT(3);
    BARRIER();
    RD_B2NS(1, cur, 1); RD_A8NS(0, cur, 1, 0);  // p3's (6); guarded by VMCNT above
    LGKM(6); MFMA8S(1, 1, 0);
    BARRIER();
    // p3
    STG_A2(nb, 1, t + 1);
    BARRIER();
    RD_A8NS(1, cur, 1, 1);                // p4's af (4)
    LGKM(4); MFMA8S(0, 0, 1);
    BARRIER();
    // p4
    STG_B1(nb, 1, t + 1);
    VMCNT(3);
    BARRIER();
    RD_B2NS(0, nb, 0); RD_A8NS(0, nb, 0, 0);    // next p1's (6); guarded by VMCNT above
    LGKM(6); MFMA8S(1, 1, 1);
    BARRIER();
    cur = nb;
  }
  // drain
  RD_A8NS(1, cur, 0, 1);
  LGKM(4); MFMA8S(0, 0, 0);
  BARRIER();
  VMCNT(0);
  BARRIER();
  RD_B2NS(1, cur, 1); RD_A8NS(0, cur, 1, 0);
  LGKM(6); MFMA8S(1, 1, 0);
  RD_A8NS(1, cur, 1, 1);
  LGKM(4); MFMA8S(0, 0, 1);
  LGKM(0); MFMA8S(1, 1, 1);

  __syncthreads();
  unsigned short* sh16 = (unsigned short*)smem;
  const int q = l15;
  float bv[2];
#pragma unroll
  for (int j = 0; j < 2; ++j) {
    const int colG = tileN + wn * 32 + j * 16 + q;
    if (BIASMODE == BIAS_QKV) {
      bv[j] = (colG < 1024) ? bias0[colG] : (colG < 2048 ? 0.f : bias1[colG - 2048]);
    } else {
      bv[j] = bias0[colG];
    }
  }
#pragma unroll
  for (int h = 0; h < 2; ++h) {
    if (wm == h) {
#pragma unroll
      for (int i = 0; i < 8; ++i)
#pragma unroll
        for (int j = 0; j < 2; ++j)
#pragma unroll
          for (int r = 0; r < 4; ++r) {
            float v = acc[i][j][r] + bv[j];
            if (ACT == ACT_GELU) v = gelu_fast(v);
            sh16[(i * 16 + g * 4 + r) * 136 + wn * 32 + j * 16 + q] = f2bf_bits(v);
          }
    }
    __syncthreads();
#pragma unroll
    for (int pass = 0; pass < 4; ++pass) {
      const int idx = pass * 512 + tid;
      const int row = idx >> 4, c16 = idx & 15;
      uint4 val = *reinterpret_cast<const uint4*>(&sh16[row * 136 + c16 * 8]);
      *reinterpret_cast<uint4*>(
          (unsigned short*)C + (size_t)(tileM + h * 128 + row) * (size_t)N +
          tileN + c16 * 8) = val;
    }
    __syncthreads();
  }
}

// ============== fallback 128x128 GEMM (round-3 verified) ====================
template <int GATHER, int BIASMODE, int ACT>
__global__ __launch_bounds__(256, 2) void gemm_bt(
    const unsigned short* __restrict__ A, const unsigned short* __restrict__ B,
    const float* __restrict__ bias0, const float* __restrict__ bias1,
    bf16* __restrict__ C, int M, int N, int K)
{
  __shared__ __align__(16) unsigned short sh[128 * 136];
  unsigned short* As = sh;
  unsigned short* Bs = sh + 8192;

  const int tid = threadIdx.x;
  const int lane = tid & 63;
  const int wave = tid >> 6;
  const int waveM = wave >> 1, waveN = wave & 1;
  const int tileM = blockIdx.x * 128, tileN = blockIdx.y * 128;

  const int row0 = tid >> 3;
  const int kOff = (tid & 7) * 8;

  const unsigned short* ag[4];
  const unsigned short* bg[4];
  unsigned short* al[4];
  unsigned short* bl[4];
#pragma unroll
  for (int t = 0; t < 4; ++t) {
    int gr = tileM + row0 + 32 * t;
    int sr = GATHER ? gather_win_row(gr) : gr;
    ag[t] = A + (size_t)sr * (size_t)K + (size_t)kOff;
    bg[t] = B + (size_t)(tileN + row0 + 32 * t) * (size_t)K + (size_t)kOff;
    al[t] = &As[(row0 + 32 * t) * 64 + kOff];
    bl[t] = &Bs[(row0 + 32 * t) * 64 + kOff];
  }

  floatx4 acc[4][4];
#pragma unroll
  for (int i = 0; i < 4; ++i)
#pragma unroll
    for (int j = 0; j < 4; ++j) acc[i][j] = (floatx4){0.f, 0.f, 0.f, 0.f};

  for (int k0 = 0; k0 < K; k0 += 64) {
#pragma unroll
    for (int t = 0; t < 4; ++t) {
      gload_lds16(ag[t] + k0, al[t]);
      gload_lds16(bg[t] + k0, bl[t]);
    }
    __syncthreads();
#pragma unroll
    for (int ks = 0; ks < 2; ++ks) {
      const int kk = ks * 32 + (lane >> 4) * 8;
      short8 afv[4], bfv[4];
#pragma unroll
      for (int i = 0; i < 4; ++i)
        afv[i] = *reinterpret_cast<const short8*>(
            &As[(waveM * 64 + i * 16 + (lane & 15)) * 64 + kk]);
#pragma unroll
      for (int j = 0; j < 4; ++j)
        bfv[j] = *reinterpret_cast<const short8*>(
            &Bs[(waveN * 64 + j * 16 + (lane & 15)) * 64 + kk]);
#pragma unroll
      for (int i = 0; i < 4; ++i)
#pragma unroll
        for (int j = 0; j < 4; ++j)
          acc[i][j] = __builtin_amdgcn_mfma_f32_16x16x32_bf16(afv[i], bfv[j], acc[i][j], 0, 0, 0);
    }
    __syncthreads();
  }

#pragma unroll
  for (int j = 0; j < 4; ++j) {
    const int colL = waveN * 64 + j * 16 + (lane & 15);
    const int colG = tileN + colL;
    float bv;
    if (BIASMODE == BIAS_QKV) {
      if (colG < 1024) bv = bias0[colG];
      else if (colG < 2048) bv = 0.f;
      else bv = bias1[colG - 2048];
    } else {
      bv = bias0[colG];
    }
#pragma unroll
    for (int i = 0; i < 4; ++i) {
      const int rL = waveM * 64 + i * 16 + ((lane >> 4) * 4);
#pragma unroll
      for (int r = 0; r < 4; ++r) {
        float v = acc[i][j][r] + bv;
        if (ACT == ACT_GELU) v = gelu_fast(v);
        sh[(rL + r) * 136 + colL] = f2bf_bits(v);
      }
    }
  }
  __syncthreads();
  {
    const int rowR = tid >> 4;
    const int colR = (tid & 15) * 8;
#pragma unroll
    for (int s = 0; s < 8; ++s) {
      const int row = s * 16 + rowR;
      uint4 val = *reinterpret_cast<const uint4*>(&sh[row * 136 + colR]);
      *reinterpret_cast<uint4*>(
          (unsigned short*)C + (size_t)(tileM + row) * (size_t)N + tileN + colR) = val;
    }
  }
}

// CPB MLP: regenerate the static log-spaced coord table and run 2->512->16 MLP.
// TBL layout: [16 heads][225] f32 (head-major for wave-contiguous loads).
__global__ __launch_bounds__(512) void cpb_kernel(
    const float* __restrict__ w1, const float* __restrict__ b1,
    const float* __restrict__ w2, float* __restrict__ TBL)
{
  __shared__ float hid[512];
  const int i = blockIdx.x;   // 0..224
  const int j = threadIdx.x;  // 0..511
  const float d0 = ((float)(i / 15) - 7.f) / 7.f;
  const float d1 = ((float)(i % 15) - 7.f) / 7.f;
  const float t0 = copysignf(log2f(1.f + fabsf(d0)), d0);
  const float t1 = copysignf(log2f(1.f + fabsf(d1)), d1);
  float hv = t0 * w1[j * 2] + t1 * w1[j * 2 + 1] + b1[j];
  hid[j] = fmaxf(hv, 0.f);
  __syncthreads();
  if (j < 16) {
    float s = 0.f;
    for (int jj = 0; jj < 512; ++jj) s += w2[j * 512 + jj] * hid[jj];
    TBL[j * 225 + i] = 16.f / (1.f + expf(-s));
  }
}

// MFMA attention: one wave per (window, head); block = 1 window x 4 heads.
__global__ __launch_bounds__(256) void attn_mfma(
    const bf16* __restrict__ QKV, const float* __restrict__ TBL,
    const float* __restrict__ ls, bf16* __restrict__ ATT)
{
  __shared__ __align__(16) unsigned short Ps[4][64][72];
  __shared__ float tbs[4][226];
  __shared__ int ids[64];

  const int tid = threadIdx.x;
  const int w = tid >> 6;
  const int l = tid & 63;
  const int q = l & 15;
  const int g = l >> 4;
  const int bw = blockIdx.x >> 2;
  const int h = (blockIdx.x & 3) * 4 + w;

  const unsigned short* qkvu = (const unsigned short*)QKV;
  const size_t rbase = (size_t)(bw * 64) * 3072;

  if (tid < 64) {
    const int w2 = bw & 3, wi = w2 >> 1, wj = w2 & 1;
    const int r = tid >> 3, c = tid & 7;
    const int rr = (wi == 0) ? 0 : (r < 4 ? 1 : 2);
    const int rc = (wj == 0) ? 0 : (c < 4 ? 1 : 2);
    ids[tid] = rr * 3 + rc;
  }
#pragma unroll
  for (int i = 0; i < 4; ++i) {
    int idx = i * 64 + l;
    if (idx < 225) tbs[w][idx] = TBL[h * 225 + idx];
  }
  __syncthreads();

  short8 kf[4][2], qf[4][2];
#pragma unroll
  for (int i = 0; i < 4; ++i) {
    const unsigned short* rp = qkvu + rbase + (size_t)(16 * i + q) * 3072 + h * 64 + g * 8;
    qf[i][0] = *reinterpret_cast<const short8*>(rp);
    qf[i][1] = *reinterpret_cast<const short8*>(rp + 32);
    kf[i][0] = *reinterpret_cast<const short8*>(rp + 1024);
    kf[i][1] = *reinterpret_cast<const short8*>(rp + 1024 + 32);
  }

  float rk4[4], rq4[4];
#pragma unroll
  for (int i = 0; i < 4; ++i) {
    float sk = 0.f, sq = 0.f;
#pragma unroll
    for (int ks = 0; ks < 2; ++ks)
#pragma unroll
      for (int e = 0; e < 8; ++e) {
        float kv = bf2f((unsigned short)kf[i][ks][e]);
        float qv = bf2f((unsigned short)qf[i][ks][e]);
        sk += kv * kv; sq += qv * qv;
      }
    sk += __shfl_xor(sk, 16); sk += __shfl_xor(sk, 32);
    sq += __shfl_xor(sq, 16); sq += __shfl_xor(sq, 32);
    rk4[i] = 1.f / fmaxf(sqrtf(sk), 1e-12f);
    rq4[i] = 1.f / fmaxf(sqrtf(sq), 1e-12f);
  }
  const float scl = expf(fminf(ls[h], 4.60517019f));
  float rqs[4];
#pragma unroll
  for (int j = 0; j < 4; ++j) rqs[j] = rq4[j] * scl;

  floatx4 acc[4][4];
#pragma unroll
  for (int i = 0; i < 4; ++i)
#pragma unroll
    for (int j = 0; j < 4; ++j) acc[i][j] = (floatx4){0.f, 0.f, 0.f, 0.f};
#pragma unroll
  for (int ks = 0; ks < 2; ++ks)
#pragma unroll
    for (int i = 0; i < 4; ++i)
#pragma unroll
      for (int j = 0; j < 4; ++j)
        acc[i][j] = __builtin_amdgcn_mfma_f32_16x16x32_bf16(kf[i][ks], qf[j][ks], acc[i][j], 0, 0, 0);

  short8 vf[4][2];
  const unsigned short* vbase = qkvu + rbase + 2048 + h * 64;
#pragma unroll
  for (int jp = 0; jp < 4; ++jp)
#pragma unroll
    for (int ks = 0; ks < 2; ++ks) {
      const int m0 = ks * 32 + g * 8;
      const unsigned short* vp = vbase + 16 * jp + q;
      union { short8 v; unsigned short u[8]; } pk;
#pragma unroll
      for (int e = 0; e < 8; ++e)
        pk.u[e] = vp[(size_t)(m0 + e) * 3072];
      vf[jp][ks] = pk.v;
    }

  int idn[4], rtn[4], ctn[4];
#pragma unroll
  for (int j = 0; j < 4; ++j) {
    const int n = 16 * j + q;
    rtn[j] = n >> 3; ctn[j] = n & 7; idn[j] = ids[n];
  }
#pragma unroll
  for (int i = 0; i < 4; ++i) {
#pragma unroll
    for (int r = 0; r < 4; ++r) {
      const int m = 16 * i + 4 * g + r;
      const float rkm = __shfl(rk4[i], 4 * g + r);
      const int rm = m >> 3, cm = m & 7;
      const int idm = ids[m];
#pragma unroll
      for (int j = 0; j < 4; ++j) {
        float v = acc[i][j][r] * (rkm * rqs[j]) +
                  tbs[w][(rtn[j] - rm + 7) * 15 + (ctn[j] - cm + 7)];
        if (idm != idn[j]) v -= 100.f;
        acc[i][j][r] = v;
      }
    }
  }

  float rs4[4];
#pragma unroll
  for (int j = 0; j < 4; ++j) {
    float mx = acc[0][j][0];
#pragma unroll
    for (int i = 0; i < 4; ++i)
#pragma unroll
      for (int r = 0; r < 4; ++r) mx = fmaxf(mx, acc[i][j][r]);
    mx = fmaxf(mx, __shfl_xor(mx, 16));
    mx = fmaxf(mx, __shfl_xor(mx, 32));
    float sm = 0.f;
#pragma unroll
    for (int i = 0; i < 4; ++i)
#pragma unroll
      for (int r = 0; r < 4; ++r) {
        float e = __expf(acc[i][j][r] - mx);
        acc[i][j][r] = e; sm += e;
      }
    sm += __shfl_xor(sm, 16);
    sm += __shfl_xor(sm, 32);
    rs4[j] = 1.f / sm;
  }

#pragma unroll
  for (int j = 0; j < 4; ++j)
#pragma unroll
    for (int i = 0; i < 4; ++i) {
      uint2v pw;
      pw[0] = (unsigned int)f2bf_bits(acc[i][j][0]) |
              ((unsigned int)f2bf_bits(acc[i][j][1]) << 16);
      pw[1] = (unsigned int)f2bf_bits(acc[i][j][2]) |
              ((unsigned int)f2bf_bits(acc[i][j][3]) << 16);
      *reinterpret_cast<uint2v*>(&Ps[w][16 * j + q][16 * i + 4 * g]) = pw;
    }

  floatx4 o[4][4];
#pragma unroll
  for (int i = 0; i < 4; ++i)
#pragma unroll
    for (int j = 0; j < 4; ++j) o[i][j] = (floatx4){0.f, 0.f, 0.f, 0.f};
#pragma unroll
  for (int ks = 0; ks < 2; ++ks) {
    short8 pa[4];
#pragma unroll
    for (int i2 = 0; i2 < 4; ++i2)
      pa[i2] = *reinterpret_cast<const short8*>(&Ps[w][16 * i2 + q][ks * 32 + g * 8]);
#pragma unroll
    for (int i2 = 0; i2 < 4; ++i2)
#pragma unroll
      for (int j2 = 0; j2 < 4; ++j2)
        o[i2][j2] = __builtin_amdgcn_mfma_f32_16x16x32_bf16(pa[i2], vf[j2][ks], o[i2][j2], 0, 0, 0);
  }

  unsigned short* op = (unsigned short*)ATT + (size_t)(bw * 64) * 1024 + h * 64;
#pragma unroll
  for (int i2 = 0; i2 < 4; ++i2)
#pragma unroll
    for (int r = 0; r < 4; ++r) {
      const float rsn = __shfl(rs4[i2], 4 * g + r);
      const int row = 16 * i2 + 4 * g + r;
#pragma unroll
      for (int j2 = 0; j2 < 4; ++j2)
        op[(size_t)row * 1024 + 16 * j2 + q] = f2bf_bits(o[i2][j2][r] * rsn);
    }
}

// out[tok] = base[tok] + LN(src[maprow(tok)]). One WAVE per token, 4 tokens/block.
template <bool GATHER, bool WB>
__global__ __launch_bounds__(256) void ln_residual(
    const bf16* __restrict__ src, const float* base,
    const float* __restrict__ gw, const float* __restrict__ gb,
    float* out, bf16* __restrict__ out_bf)
{
  const int tok = blockIdx.x * 4 + (threadIdx.x >> 6);
  const int lane = threadIdx.x & 63;
  int srow;
  if (GATHER) {
    const int bt = tok >> 8, rem = tok & 255, i = rem >> 4, j = rem & 15;
    const int p = (i + 12) & 15, qq = (j + 12) & 15;
    srow = (bt * 4 + (p >> 3) * 2 + (qq >> 3)) * 64 + (p & 7) * 8 + (qq & 7);
  } else {
    srow = tok;
  }
  const unsigned short* sp = (const unsigned short*)src + (size_t)srow * 1024 + lane * 16;
  short8 lv0 = *reinterpret_cast<const short8*>(sp);
  short8 lv1 = *reinterpret_cast<const short8*>(sp + 8);
  float v[16];
  float s = 0.f, sq = 0.f;
#pragma unroll
  for (int u = 0; u < 8; ++u) {
    float f = bf2f((unsigned short)lv0[u]); v[u] = f; s += f; sq += f * f;
    float g = bf2f((unsigned short)lv1[u]); v[u + 8] = g; s += g; sq += g * g;
  }
#pragma unroll
  for (int off = 32; off > 0; off >>= 1) { s += __shfl_xor(s, off); sq += __shfl_xor(sq, off); }
  const float mean = s * (1.f / 1024.f);
  const float var = sq * (1.f / 1024.f) - mean * mean;
  const float rstd = rsqrtf(var + 1e-5f);

  const float* bp = base + (size_t)tok * 1024 + lane * 16;
  float* op = out + (size_t)tok * 1024 + lane * 16;
  unsigned short* obp = WB ? ((unsigned short*)out_bf + (size_t)tok * 1024 + lane * 16) : nullptr;
  union { short8 v; unsigned short u[8]; } ob0, ob1;
#pragma unroll
  for (int q4 = 0; q4 < 4; ++q4) {
    float4 b4 = *reinterpret_cast<const float4*>(bp + q4 * 4);
    float bl[4] = {b4.x, b4.y, b4.z, b4.w};
    float4 o4;
    float* ol = (float*)&o4;
#pragma unroll
    for (int u = 0; u < 4; ++u) {
      const int c = lane * 16 + q4 * 4 + u;
      ol[u] = bl[u] + (v[q4 * 4 + u] - mean) * rstd * gw[c] + gb[c];
      if (WB) {
        if (q4 < 2) ob0.u[q4 * 4 + u] = f2bf_bits(ol[u]);
        else ob1.u[(q4 - 2) * 4 + u] = f2bf_bits(ol[u]);
      }
    }
    *reinterpret_cast<float4*>(op + q4 * 4) = o4;
  }
  if (WB) {
    *reinterpret_cast<short8*>(obp) = ob0.v;
    *reinterpret_cast<short8*>(obp + 8) = ob1.v;
  }
}

extern "C" void kernel_launch(void* const* d_in, const int* in_sizes, int n_in,
                              void* d_out, int out_size, void* d_ws, size_t ws_size,
                              hipStream_t stream) {
  (void)in_sizes; (void)n_in; (void)out_size;
  const float* x      = (const float*)d_in[0];
  const float* qkv_w  = (const float*)d_in[1];
  const float* q_bias = (const float*)d_in[2];
  const float* v_bias = (const float*)d_in[3];
  const float* lscale = (const float*)d_in[4];
  const float* cpb_w1 = (const float*)d_in[5];
  const float* cpb_b1 = (const float*)d_in[6];
  const float* cpb_w2 = (const float*)d_in[7];
  const float* proj_w = (const float*)d_in[8];
  const float* proj_b = (const float*)d_in[9];
  const float* n1w    = (const float*)d_in[10];
  const float* n1b    = (const float*)d_in[11];
  const float* fc1_w  = (const float*)d_in[12];
  const float* fc1_b  = (const float*)d_in[13];
  const float* fc2_w  = (const float*)d_in[14];
  const float* fc2_b  = (const float*)d_in[15];
  const float* n2w    = (const float*)d_in[16];
  const float* n2b    = (const float*)d_in[17];
  float* out = (float*)d_out;

  static int attr_ok = -1;
  if (attr_ok < 0) {
    hipError_t e1 = hipFuncSetAttribute(
        reinterpret_cast<const void*>(&gemm8p<0, BIAS_SIMPLE, ACT_GELU>),
        hipFuncAttributeMaxDynamicSharedMemorySize, 131072);
    hipError_t e2 = hipFuncSetAttribute(
        reinterpret_cast<const void*>(&gemm8pn<1, BIAS_QKV, ACT_NONE>),
        hipFuncAttributeMaxDynamicSharedMemorySize, 98304);
    hipError_t e3 = hipFuncSetAttribute(
        reinterpret_cast<const void*>(&gemm8pn<0, BIAS_SIMPLE, ACT_NONE>),
        hipFuncAttributeMaxDynamicSharedMemorySize, 98304);
    attr_ok = (e1 == hipSuccess && e2 == hipSuccess && e3 == hipSuccess) ? 1 : 0;
  }

  char* ws = (char*)d_ws;
  bf16*  QKV  = (bf16*)(ws);                          // [8192,3072]
  bf16*  H    = (bf16*)(ws);                          // [8192,4096]
  bf16*  ATT  = (bf16*)(ws + 67108864);               // [8192,1024]
  bf16*  XSB  = (bf16*)(ws + 67108864);               // [8192,1024]
  bf16*  F2   = (bf16*)(ws + 67108864);               // [8192,1024]
  bf16*  XBF  = (bf16*)(ws + 83886080);               // [8192,1024]
  bf16*  PROJ = (bf16*)(ws + 83886080);               // [8192,1024]
  float* TBL  = (float*)(ws + 100663296);             // [16,225] f32

  const bool persist = ws_size >= (size_t)125845504;  // 120 MB
  bf16* WQKV, *WPROJ, *WF1, *WF2;
  if (persist) {
    WQKV  = (bf16*)(ws + 100679680);
    WPROJ = (bf16*)(ws + 106971136);
    WF1   = (bf16*)(ws + 109068288);
    WF2   = (bf16*)(ws + 117456896);
  } else {
    WQKV  = (bf16*)(ws + 67108864);
    WPROJ = (bf16*)(ws + 50331648);
    WF1   = (bf16*)(ws + 83886080);
    WF2   = (bf16*)(ws + 83886080 + 8388608);
  }

  cpb_kernel<<<225, 512, 0, stream>>>(cpb_w1, cpb_b1, cpb_w2, TBL);
  if (persist) {
    cvt_bf16<<<1536, 256, 0, stream>>>(qkv_w, WQKV, 3145728);
    cvt_bf16<<<512, 256, 0, stream>>>(proj_w, WPROJ, 1048576);
    cvt_bf16<<<2048, 256, 0, stream>>>(fc1_w, WF1, 4194304);
    cvt_bf16<<<2048, 256, 0, stream>>>(fc2_w, WF2, 4194304);
  }

  for (int ch = 0; ch < 4; ++ch) {
    const size_t tokBase = (size_t)ch * 8192;
    const float* x_c = x + tokBase * 1024;
    float* out_c = out + tokBase * 1024;

    cvt_bf16<<<4096, 256, 0, stream>>>(x_c, XBF, 8388608);
    if (!persist) {
      cvt_bf16<<<1536, 256, 0, stream>>>(qkv_w, WQKV, 3145728);
      cvt_bf16<<<512, 256, 0, stream>>>(proj_w, WPROJ, 1048576);
    }

    if (attr_ok) {
      gemm8pn<1, BIAS_QKV, ACT_NONE><<<dim3(32, 24), 512, 98304, stream>>>(
          (const unsigned short*)XBF, (const unsigned short*)WQKV,
          q_bias, v_bias, QKV, 8192, 3072, 1024);
    } else {
      gemm_bt<1, BIAS_QKV, ACT_NONE><<<dim3(64, 24), 256, 0, stream>>>(
          (const unsigned short*)XBF, (const unsigned short*)WQKV,
          q_bias, v_bias, QKV, 8192, 3072, 1024);
    }
    attn_mfma<<<512, 256, 0, stream>>>(QKV, TBL, lscale, ATT);
    if (attr_ok) {
      gemm8pn<0, BIAS_SIMPLE, ACT_NONE><<<dim3(32, 8), 512, 98304, stream>>>(
          (const unsigned short*)ATT, (const unsigned short*)WPROJ,
          proj_b, nullptr, PROJ, 8192, 1024, 1024);
    } else {
      gemm_bt<0, BIAS_SIMPLE, ACT_NONE><<<dim3(64, 8), 256, 0, stream>>>(
          (const unsigned short*)ATT, (const unsigned short*)WPROJ,
          proj_b, nullptr, PROJ, 8192, 1024, 1024);
    }
    ln_residual<true, true><<<2048, 256, 0, stream>>>(PROJ, x_c, n1w, n1b, out_c, XSB);
    if (!persist) {
      cvt_bf16<<<2048, 256, 0, stream>>>(fc1_w, WF1, 4194304);
      cvt_bf16<<<2048, 256, 0, stream>>>(fc2_w, WF2, 4194304);
    }
    if (attr_ok) {
      gemm8p<0, BIAS_SIMPLE, ACT_GELU><<<dim3(32, 16), 512, 131072, stream>>>(
          (const unsigned short*)XSB, (const unsigned short*)WF1,
          fc1_b, nullptr, H, 8192, 4096, 1024);
      gemm8pn<0, BIAS_SIMPLE, ACT_NONE><<<dim3(32, 8), 512, 98304, stream>>>(
          (const unsigned short*)H, (const unsigned short*)WF2,
          fc2_b, nullptr, F2, 8192, 1024, 4096);
    } else {
      gemm_bt<0, BIAS_SIMPLE, ACT_GELU><<<dim3(64, 32), 256, 0, stream>>>(
          (const unsigned short*)XSB, (const unsigned short*)WF1,
          fc1_b, nullptr, H, 8192, 4096, 1024);
      gemm_bt<0, BIAS_SIMPLE, ACT_NONE><<<dim3(64, 8), 256, 0, stream>>>(
          (const unsigned short*)H, (const unsigned short*)WF2,
          fc2_b, nullptr, F2, 8192, 1024, 4096);
    }
    ln_residual<false, false><<<2048, 256, 0, stream>>>(F2, out_c, n2w, n2b, out_c, nullptr);
  }
}